// Round 8
// baseline (512.860 us; speedup 1.0000x reference)
//
#include <hip/hip_runtime.h>
#include <cstdint>
#include <cstddef>

typedef __bf16 bf16;
typedef __bf16 bf16x4 __attribute__((ext_vector_type(4)));
typedef __bf16 bf16x8 __attribute__((ext_vector_type(8)));
typedef float  f32x4  __attribute__((ext_vector_type(4)));

#define GLD_LDS16(gp, lp) \
  __builtin_amdgcn_global_load_lds((__attribute__((address_space(1))) void*)(gp), \
                                   (__attribute__((address_space(3))) void*)(lp), 16, 0, 0)

__device__ __forceinline__ f32x4 f32x4_zero(){ f32x4 v; v[0]=0.f; v[1]=0.f; v[2]=0.f; v[3]=0.f; return v; }

__device__ __forceinline__ f32x4 mfma16x16x32(bf16x8 a, bf16x8 b, f32x4 c){
  return __builtin_amdgcn_mfma_f32_16x16x32_bf16(a, b, c, 0, 0, 0);
}
// fragment of a 64-col bf16 LDS array (stride 64), LINEAR layout (phaseB kernels)
__device__ __forceinline__ bf16x8 frag64(const bf16* base, int row0, int kk, int lane){
  return *(const bf16x8*)&base[(row0 + (lane&15))*64 + kk*32 + (lane>>4)*8];
}
// fragment of a 64-col bf16 LDS array with XOR bank-swizzle: elem ^= (row&7)<<3
__device__ __forceinline__ bf16x8 fragSwz(const bf16* base, int row0, int kk, int lane){
  const int row = row0 + (lane&15);
  const int off = (kk*32 + (lane>>4)*8) ^ ((row&7)<<3);
  return *(const bf16x8*)&base[row*64 + off];
}
struct bf2 { bf16 h, l; };
__device__ __forceinline__ bf2 split2(float v){
  bf2 r; r.h = (bf16)v; r.l = (bf16)(v - (float)r.h); return r;
}
// pack hi/lo split of v into one dword: bits(h) | bits(l)<<16
__device__ __forceinline__ uint32_t pack2(float v){
  bf2 s = split2(v);
  union { bf16 b; uint16_t u; } uh, ul;
  uh.b = s.h; ul.b = s.l;
  return (uint32_t)uh.u | ((uint32_t)ul.u << 16);
}

// ---------------------------------------------------------------- K0a: x -> hi/lo bf16 planes
__global__ __launch_bounds__(256) void k_cvt_x(const float* __restrict__ x,
                                               bf16* __restrict__ xh, bf16* __restrict__ xl, int n4){
  int i = blockIdx.x*256 + threadIdx.x;
  if (i < n4){
    float4 v = ((const float4*)x)[i];
    bf16x4 h, l;
    bf2 t0 = split2(v.x); h[0]=t0.h; l[0]=t0.l;
    bf2 t1 = split2(v.y); h[1]=t1.h; l[1]=t1.l;
    bf2 t2 = split2(v.z); h[2]=t2.h; l[2]=t2.l;
    bf2 t3 = split2(v.w); h[3]=t3.h; l[3]=t3.l;
    ((bf16x4*)xh)[i] = h;
    ((bf16x4*)xl)[i] = l;
  }
}

// ---------------------------------------------------------------- K0b: W[k][n] -> Wt hi/lo [n][k]
__global__ __launch_bounds__(256) void k_transpose_w(const float* __restrict__ W,
                                                     bf16* __restrict__ Wth, bf16* __restrict__ Wtl){
  __shared__ float tile[32][33];
  const int k0 = blockIdx.x*32, n0 = blockIdx.y*32;
  const int r = threadIdx.x >> 3, c4 = (threadIdx.x & 7)*4;
  float4 v = *(const float4*)&W[(size_t)(k0+r)*1024 + n0 + c4];
  tile[r][c4+0]=v.x; tile[r][c4+1]=v.y; tile[r][c4+2]=v.z; tile[r][c4+3]=v.w;
  __syncthreads();
  bf16x4 h, l;
  bf2 t0 = split2(tile[c4+0][r]); h[0]=t0.h; l[0]=t0.l;
  bf2 t1 = split2(tile[c4+1][r]); h[1]=t1.h; l[1]=t1.l;
  bf2 t2 = split2(tile[c4+2][r]); h[2]=t2.h; l[2]=t2.l;
  bf2 t3 = split2(tile[c4+3][r]); h[3]=t3.h; l[3]=t3.l;
  *(bf16x4*)&Wth[(size_t)(n0+r)*1024 + k0 + c4] = h;
  *(bf16x4*)&Wtl[(size_t)(n0+r)*1024 + k0 + c4] = l;
}

// ---------------------------------------------------------------- K0c: Walpha/Wbeta [1024][16] -> WabT hi/lo bf16 [32][1024]
__global__ __launch_bounds__(256) void k_transpose_ab(const float* __restrict__ Wa, const float* __restrict__ Wb,
                                                      bf16* __restrict__ WabTh, bf16* __restrict__ WabTl){
  int p = blockIdx.x*256 + threadIdx.x;
  if (p < 32768){
    int o = p >> 10, k = p & 1023;
    float v = (o < 16) ? Wa[k*16 + o] : Wb[k*16 + (o-16)];
    bf2 s = split2(v);
    WabTh[p] = s.h;
    WabTl[p] = s.l;
  }
}

// ---------------------------------------------------------------- K1: split-bf16 MFMA GEMM (3-product), K=1024
__global__ __launch_bounds__(256) void k_gemm3(const bf16* __restrict__ Ah, const bf16* __restrict__ Al,
                                               const bf16* __restrict__ Bth, const bf16* __restrict__ Btl,
                                               bf16* __restrict__ Cb, float* __restrict__ Cf){
  __shared__ bf16 Ash[128*32], Asl[128*32];
  __shared__ bf16 Bsh[128*32], Bsl[128*32];
  const int tid = threadIdx.x, lane = tid & 63, w = tid >> 6;
  const int wm = w >> 1, wn = w & 1;
  const size_t m0 = (size_t)blockIdx.x * 128;
  const size_t n0 = (size_t)blockIdx.y * 128;
  f32x4 acc[4][4];
  #pragma unroll
  for (int i=0;i<4;++i)
    #pragma unroll
    for (int j=0;j<4;++j) acc[i][j] = f32x4_zero();

  for (int k0 = 0; k0 < 1024; k0 += 32){
    __syncthreads();
    #pragma unroll
    for (int j = 0; j < 2; ++j){
      const int rbase = 32*w + 16*j;
      const int r = rbase + (lane >> 2);
      const int kk = k0 + (lane & 3)*8;
      GLD_LDS16(&Ah [(m0 + r)*1024 + kk], &Ash[rbase*32]);
      GLD_LDS16(&Al [(m0 + r)*1024 + kk], &Asl[rbase*32]);
      GLD_LDS16(&Bth[(n0 + r)*1024 + kk], &Bsh[rbase*32]);
      GLD_LDS16(&Btl[(n0 + r)*1024 + kk], &Bsl[rbase*32]);
    }
    __syncthreads();
    bf16x8 ah[4], al[4], bh[4], bl[4];
    #pragma unroll
    for (int t=0;t<4;++t){
      ah[t] = *(const bf16x8*)&Ash[(64*wm + 16*t + (lane&15))*32 + (lane>>4)*8];
      al[t] = *(const bf16x8*)&Asl[(64*wm + 16*t + (lane&15))*32 + (lane>>4)*8];
      bh[t] = *(const bf16x8*)&Bsh[(64*wn + 16*t + (lane&15))*32 + (lane>>4)*8];
      bl[t] = *(const bf16x8*)&Bsl[(64*wn + 16*t + (lane&15))*32 + (lane>>4)*8];
    }
    #pragma unroll
    for (int i=0;i<4;++i)
      #pragma unroll
      for (int j=0;j<4;++j){
        f32x4 t = acc[i][j];
        t = mfma16x16x32(ah[i], bh[j], t);
        t = mfma16x16x32(ah[i], bl[j], t);
        t = mfma16x16x32(al[i], bh[j], t);
        acc[i][j] = t;
      }
  }
  #pragma unroll
  for (int i=0;i<4;++i)
    #pragma unroll
    for (int j=0;j<4;++j)
      #pragma unroll
      for (int r=0;r<4;++r){
        size_t row = m0 + 64*wm + 16*i + (lane>>4)*4 + r;
        size_t col = n0 + 64*wn + 16*j + (lane&15);
        float v = acc[i][j][r];
        if (Cf) Cf[row*1024 + col] = v;
        else    Cb[row*1024 + col] = (bf16)v;
      }
}

// ---------------------------------------------------------------- K1b: single-bf16 MFMA GEMM, K=1024
// NRM: 0 = plain, 1 = fused q l2norm (0.125/||.||), 2 = fused k l2norm (1/||.||).
// Cl != nullptr -> write hi/lo bf16 split planes (Cb=hi, Cl=lo).
template<int NRM>
__global__ __launch_bounds__(256) void k_gemm1(const bf16* __restrict__ Ah, const bf16* __restrict__ Bth,
                                               bf16* __restrict__ Cb, float* __restrict__ Cf,
                                               bf16* __restrict__ Cl){
  __shared__ bf16 Ash[128*32];
  __shared__ bf16 Bsh[128*32];
  const int tid = threadIdx.x, lane = tid & 63, w = tid >> 6;
  const int wm = w >> 1, wn = w & 1;
  const size_t m0 = (size_t)blockIdx.x * 128;
  const size_t n0 = (size_t)blockIdx.y * 128;
  f32x4 acc[4][4];
  #pragma unroll
  for (int i=0;i<4;++i)
    #pragma unroll
    for (int j=0;j<4;++j) acc[i][j] = f32x4_zero();

  for (int k0 = 0; k0 < 1024; k0 += 32){
    __syncthreads();
    #pragma unroll
    for (int j = 0; j < 2; ++j){
      const int rbase = 32*w + 16*j;
      const int r = rbase + (lane >> 2);
      const int kk = k0 + (lane & 3)*8;
      GLD_LDS16(&Ah [(m0 + r)*1024 + kk], &Ash[rbase*32]);
      GLD_LDS16(&Bth[(n0 + r)*1024 + kk], &Bsh[rbase*32]);
    }
    __syncthreads();
    bf16x8 ah[4], bh[4];
    #pragma unroll
    for (int t=0;t<4;++t){
      ah[t] = *(const bf16x8*)&Ash[(64*wm + 16*t + (lane&15))*32 + (lane>>4)*8];
      bh[t] = *(const bf16x8*)&Bsh[(64*wn + 16*t + (lane&15))*32 + (lane>>4)*8];
    }
    #pragma unroll
    for (int i=0;i<4;++i)
      #pragma unroll
      for (int j=0;j<4;++j)
        acc[i][j] = mfma16x16x32(ah[i], bh[j], acc[i][j]);
  }
  #pragma unroll
  for (int i=0;i<4;++i)
    #pragma unroll
    for (int r=0;r<4;++r){
      float sc = 1.f;
      if (NRM){
        float ss = 0.f;
        #pragma unroll
        for (int j=0;j<4;++j) ss += acc[i][j][r]*acc[i][j][r];
        ss += __shfl_xor(ss, 1); ss += __shfl_xor(ss, 2);
        ss += __shfl_xor(ss, 4); ss += __shfl_xor(ss, 8);
        sc = (NRM==1 ? 0.125f : 1.0f) / fmaxf(sqrtf(ss), 1e-12f);
      }
      #pragma unroll
      for (int j=0;j<4;++j){
        size_t row = m0 + 64*wm + 16*i + (lane>>4)*4 + r;
        size_t col = n0 + 64*wn + 16*j + (lane&15);
        float v = acc[i][j][r]*sc;
        if (Cl){ bf2 sp = split2(v); Cb[row*1024 + col] = sp.h; Cl[row*1024 + col] = sp.l; }
        else if (Cf) Cf[row*1024 + col] = v;
        else         Cb[row*1024 + col] = (bf16)v;
      }
    }
}

// ---------------------------------------------------------------- K2: alpha/beta projections as split-bf16 MFMA GEMM
__global__ __launch_bounds__(256) void k_ab_gemm(const bf16* __restrict__ xh, const bf16* __restrict__ xl,
    const bf16* __restrict__ WabTh, const bf16* __restrict__ WabTl,
    const float* __restrict__ A_log, const float* __restrict__ dt_bias,
    float* __restrict__ logA, float* __restrict__ betap){
  __shared__ bf16 Ash[2][2048], Asl[2][2048];   // 32 rows x 64 k per buffer
  const int tid = threadIdx.x, lane = tid & 63, w = tid >> 6;
  const int mt = w >> 1, nt = w & 1;
  const size_t m0 = (size_t)blockIdx.x * 32;
  const int srow = tid >> 3;
  const int scol = 8*((tid & 7) ^ (srow & 7));
  const size_t sg = (m0 + srow)*1024 + scol;

  f32x4 acc = f32x4_zero();
  GLD_LDS16(&xh[sg], &Ash[0][w*512]);
  GLD_LDS16(&xl[sg], &Asl[0][w*512]);
  for (int s = 0; s < 16; ++s){
    const int cur = s & 1;
    __syncthreads();                    // implicit vmcnt(0): buf[cur] staged
    if (s + 1 < 16){
      const size_t g = sg + (size_t)(s+1)*64;
      GLD_LDS16(&xh[g], &Ash[cur^1][w*512]);
      GLD_LDS16(&xl[g], &Asl[cur^1][w*512]);
    }
    const int k0 = s*64;
    #pragma unroll
    for (int kk = 0; kk < 2; ++kk){
      bf16x8 aH = fragSwz(Ash[cur], 16*mt, kk, lane);
      bf16x8 aL = fragSwz(Asl[cur], 16*mt, kk, lane);
      const size_t bo = (size_t)(16*nt + (lane&15))*1024 + k0 + kk*32 + (lane>>4)*8;
      bf16x8 bH = *(const bf16x8*)&WabTh[bo];
      bf16x8 bL = *(const bf16x8*)&WabTl[bo];
      acc = mfma16x16x32(aH, bH, acc);
      acc = mfma16x16x32(aH, bL, acc);
      acc = mfma16x16x32(aL, bH, acc);
    }
  }
  const int col = lane & 15;
  #pragma unroll
  for (int r = 0; r < 4; ++r){
    const size_t row = m0 + 16*mt + (lane>>4)*4 + r;
    float v = acc[r];
    if (nt == 0){
      float z = v + dt_bias[col];
      float dt = (z > 20.f) ? z : log1pf(expf(z));
      logA[row*16 + col] = -expf(A_log[col]) * dt;   // log(alpha_t)
    } else {
      betap[row*16 + col] = 1.f/(1.f + expf(-v));    // beta_t
    }
  }
}

// ---------------------------------------------------------------- K3: phase A (2048 blocks, 128 thr)
// LDS 32768 -> 5 blocks/CU; (128,4) caps VGPR 128. K staged via GLD (pre-swizzled source).
// beta folded into E/RHS. Serial diag solve (r5 form). P output: PACKED hi|lo dwords
// (one u32/elem) -> epilogue is 64 coalesced dword stores, exactly r5's store pattern
// (r6 scalar-bf16 and r7 LDS-staged split epilogues both regressed ~9-10us; the packed
// format keeps phaseA store speed AND gives B1/B3 split planes via cheap bit de-interleave).
__global__ __launch_bounds__(128, 4) void k_phaseA(const bf16* __restrict__ khp, const bf16* __restrict__ klp,
    const float* __restrict__ vf, const float* __restrict__ logA, const float* __restrict__ betap,
    bf16* __restrict__ Wg, bf16* __restrict__ Dg,
    uint32_t* __restrict__ Pg, bf16* __restrict__ Bg){
  __shared__ bf16  Kh[4096], Kl_[4096];   // 8 KiB + 8 KiB
  __shared__ float Ef[4096];              // 16 KiB; row 0 = lg cumsum
  bf16* DT  = Kh;                         // overlay: Dsol^T (after KtT build)
  bf16* WT  = Kl_;                        // overlay: Wsol^T
  bf16* KtT = (bf16*)&Ef[2048];           // overlay: K_til^T (Ef rows 32..63, after solve)
  const int tid = threadIdx.x, lane = tid & 63, wid = tid >> 6;
  const int c = blockIdx.x, h = blockIdx.y, b = blockIdx.z;
  const size_t tokbase = (size_t)b*4096 + (size_t)c*64;
  const size_t cbase = ((size_t)((b*16 + h)*64 + c)) * 4096;

  { // async stage K tile (hi/lo) with pre-swizzled source
    const int chunk = tid & 7, r0 = tid >> 3;       // r0: wave0 0..7, wave1 8..15
    #pragma unroll
    for (int rr = 0; rr < 4; ++rr){
      const int row = 16*rr + r0;
      const size_t g = (tokbase + row)*1024 + (size_t)h*64 + 8*(chunk ^ (row & 7));
      GLD_LDS16(&khp[g], &Kh[(16*rr + 8*wid)*64]);
      if (klp) GLD_LDS16(&klp[g], &Kl_[(16*rr + 8*wid)*64]);
    }
    if (!klp){
      uint4 z4; z4.x=0; z4.y=0; z4.z=0; z4.w=0;
      for (int z = tid; z < 512; z += 128) ((uint4*)Kl_)[z] = z4;
    }
  }
  const float bet = betap[(tokbase + lane)*16 + h];   // per-lane beta_t, t = lane
  if (tid < 64){
    float la = logA[(tokbase + tid)*16 + h];
    #pragma unroll
    for (int dlt = 1; dlt < 64; dlt <<= 1){
      float o = __shfl_up(la, dlt);
      if (lane >= dlt) la += o;
    }
    Ef[tid] = la;                // lg cumsum in E row 0 (row 0 never read by solve)
  }
  __syncthreads();               // GLD staged + lg ready

  // E~[t][tau] = beta_t * (gamma_t/gamma_tau)*(k_t . k_tau), strictly lower; else 0
  #pragma unroll
  for (int tt = 0; tt < 2; ++tt){
    const int t0 = 32*wid + 16*tt;
    #pragma unroll
    for (int tu = 0; tu < 4; ++tu){
      f32x4 accm = f32x4_zero();
      #pragma unroll
      for (int kk = 0; kk < 2; ++kk){
        bf16x8 aH = fragSwz(Kh,  t0,    kk, lane);
        bf16x8 aL = fragSwz(Kl_, t0,    kk, lane);
        bf16x8 bH = fragSwz(Kh,  16*tu, kk, lane);
        bf16x8 bL = fragSwz(Kl_, 16*tu, kk, lane);
        accm = mfma16x16x32(aH, bH, accm);
        accm = mfma16x16x32(aH, bL, accm);
        accm = mfma16x16x32(aL, bH, accm);
      }
      #pragma unroll
      for (int r = 0; r < 4; ++r){
        int row = t0 + (lane>>4)*4 + r, col = 16*tu + (lane&15);
        float bR = __shfl(bet, row);   // beta folded into E row
        float ev = (col < row) ? accm[r]*__expf(Ef[row] - Ef[col])*bR : 0.f;
        if (row > 0) Ef[row*64 + col] = ev;   // row 0 never read; keeps lg intact
      }
    }
  }
  __syncthreads();   // E complete (both waves) before solve reads

  // right-looking blocked forward substitution, beta pre-folded (serial diag -- r5 form)
  float d[64];
  {
    if (wid == 0){
      #pragma unroll
      for (int t = 0; t < 64; ++t)
        d[t] = __shfl(bet, t) * vf[(tokbase + t)*1024 + h*64 + lane];
    } else {
      #pragma unroll
      for (int t = 0; t < 64; ++t){
        int ks = lane ^ ((t&7)<<3);
        d[t] = __shfl(bet, t) * __expf(Ef[t]) * ((float)Kh[t*64 + ks] + (float)Kl_[t*64 + ks]);
      }
    }
    #pragma unroll
    for (int bi = 0; bi < 4; ++bi){
      // diagonal 16x16 unit-lower solve (serial accumulate)
      #pragma unroll
      for (int tt = 0; tt < 16; ++tt){
        const int t = 16*bi + tt;
        float s = 0.f;
        #pragma unroll
        for (int j = 0; j < 16; ++j)
          if (j < tt) s += Ef[t*64 + 16*bi + j] * d[16*bi + j];
        d[t] = d[t] - s;
      }
      // trailing rank-16 update of all later blocks (independent per t)
      #pragma unroll
      for (int b2 = bi + 1; b2 < 4; ++b2)
        #pragma unroll
        for (int tt = 0; tt < 16; ++tt){
          const int t = 16*b2 + tt;
          float a0=0.f,a1=0.f,a2=0.f,a3=0.f;
          #pragma unroll
          for (int q = 0; q < 4; ++q){
            float4 e = *(const float4*)&Ef[t*64 + 16*bi + q*4];
            a0 += e.x * d[16*bi + q*4 + 0];
            a1 += e.y * d[16*bi + q*4 + 1];
            a2 += e.z * d[16*bi + q*4 + 2];
            a3 += e.w * d[16*bi + q*4 + 3];
          }
          d[t] -= (a0+a1)+(a2+a3);
        }
    }
  }
  __syncthreads();   // all Ef/Kh/Kl solve reads done

  // K_til^T[j][t] = (gamma_L/gamma_t) * k[t][j]  (built AFTER solve, into Ef rows 32..63)
  {
    const float gsc = __expf(Ef[63] - Ef[lane]);   // t == lane for the stride-128 loop
    for (int i = tid; i < 4096; i += 128){
      int t = lane, j = i >> 6;
      int ks = j ^ ((t&7)<<3);
      float kv = (float)Kh[t*64 + ks] + (float)Kl_[t*64 + ks];
      KtT[j*64 + (t ^ ((j&7)<<3))] = (bf16)(gsc * kv);
    }
  }
  __syncthreads();   // KtT built; Kh/Kl_ now dead -> DT/WT overlay safe

  const float gL = __expf(Ef[63]);   // Ef row 0 intact (KtT occupies rows 32..63 only)
  {
    bf16* myT = wid ? WT : DT;
    #pragma unroll
    for (int s4 = 0; s4 < 16; ++s4){
      bf16x4 v4;
      v4[0]=(bf16)d[s4*4+0]; v4[1]=(bf16)d[s4*4+1];
      v4[2]=(bf16)d[s4*4+2]; v4[3]=(bf16)d[s4*4+3];
      *(bf16x4*)&myT[lane*64 + ((s4*4) ^ ((lane&7)<<3))] = v4;
    }
    bf16* myG = wid ? Wg : Dg;
    #pragma unroll
    for (int t = 0; t < 64; ++t)
      myG[cbase + (size_t)t*64 + lane] = (bf16)d[t];
  }
  __syncthreads();

  // P^T[j][i] = gamma_L*I - sum_t K_til[t][j]*Wsol[t][i]  (wave0, MFMA, packed hi|lo dword out)
  // B[i][j]   =              sum_t Dsol[t][i]*K_til[t][j]  (wave1, MFMA, bf16 out)
  if (wid == 0){
    #pragma unroll
    for (int tj = 0; tj < 4; ++tj)
      #pragma unroll
      for (int ti = 0; ti < 4; ++ti){
        f32x4 acc = f32x4_zero();
        #pragma unroll
        for (int kk = 0; kk < 2; ++kk)
          acc = mfma16x16x32(fragSwz(KtT, 16*tj, kk, lane), fragSwz(WT, 16*ti, kk, lane), acc);
        #pragma unroll
        for (int r = 0; r < 4; ++r){
          int row = 16*tj + (lane>>4)*4 + r, col = 16*ti + (lane&15);
          float v = ((row == col) ? gL : 0.f) - acc[r];
          Pg[cbase + (size_t)row*64 + col] = pack2(v);
        }
      }
  } else {
    #pragma unroll
    for (int ti = 0; ti < 4; ++ti)
      #pragma unroll
      for (int tj = 0; tj < 4; ++tj){
        f32x4 acc = f32x4_zero();
        #pragma unroll
        for (int kk = 0; kk < 2; ++kk)
          acc = mfma16x16x32(fragSwz(DT, 16*ti, kk, lane), fragSwz(KtT, 16*tj, kk, lane), acc);
        #pragma unroll
        for (int r = 0; r < 4; ++r){
          int row = 16*ti + (lane>>4)*4 + r, col = 16*tj + (lane&15);
          Bg[cbase + (size_t)row*64 + col] = (bf16)acc[r];
        }
      }
  }
}

// ---------------------------------------------------------------- K4a: segment composition (256 blocks: 8 seg x 32 chains)
// P arrives as packed hi|lo dwords -> de-interleave with bit ops (no fp split2)
__global__ __launch_bounds__(256) void k_phaseB1(const uint32_t* __restrict__ Pg,
                                                 const bf16* __restrict__ Bg,
                                                 float* __restrict__ PsegT, float* __restrict__ BsegF){
  __shared__ bf16 PaccH[4096], PaccL[4096], BaccH[4096], BaccL[4096];
  __shared__ bf16 PcH[4096], PcL[4096];
  __shared__ bf16 BcS[4096];
  const int tid = threadIdx.x, lane = tid & 63, w = tid >> 6;
  const int seg = blockIdx.x;
  const size_t chain = blockIdx.y;
  f32x4 Pr[4], Br[4];
  #pragma unroll
  for (int it = 0; it < 4; ++it){
    #pragma unroll
    for (int r = 0; r < 4; ++r){
      int row = 16*w + (lane>>4)*4 + r, col = 16*it + (lane&15);
      Pr[it][r] = (row == col) ? 1.f : 0.f;   // Pacc = I
      Br[it][r] = 0.f;                        // Bacc = 0
    }
  }
  for (int i = 0; i < 8; ++i){
    const size_t cb = (chain*64 + (size_t)seg*8 + i)*4096;
    #pragma unroll
    for (int it = 0; it < 4; ++it)
      #pragma unroll
      for (int r = 0; r < 4; ++r){
        int row = 16*w + (lane>>4)*4 + r, col = 16*it + (lane&15);
        bf2 sp = split2(Pr[it][r]); PaccH[row*64+col] = sp.h; PaccL[row*64+col] = sp.l;
        bf2 sb = split2(Br[it][r]); BaccH[row*64+col] = sb.h; BaccL[row*64+col] = sb.l;
      }
    __syncthreads();   // prev iter's MFMA done -> safe to overwrite PcH/L
    for (int j = tid; j < 1024; j += 256){
      uint4 p = ((const uint4*)(Pg + cb))[j];   // 4 packed elems
      uint2 hh, ll;
      hh.x = (p.x & 0xFFFFu) | (p.y << 16);
      ll.x = (p.x >> 16)     | (p.y & 0xFFFF0000u);
      hh.y = (p.z & 0xFFFFu) | (p.w << 16);
      ll.y = (p.z >> 16)     | (p.w & 0xFFFF0000u);
      ((uint2*)PcH)[j] = hh;
      ((uint2*)PcL)[j] = ll;
    }
    for (int j = tid; j < 512; j += 256)
      ((uint4*)BcS)[j] = ((const uint4*)(Bg + cb))[j];
    __syncthreads();
    f32x4 nP[4], nB[4];
    #pragma unroll
    for (int it = 0; it < 4; ++it){ nP[it] = f32x4_zero(); nB[it] = f32x4_zero(); }
    #pragma unroll
    for (int kk = 0; kk < 2; ++kk){
      bf16x8 aPH = frag64(PaccH, 16*w, kk, lane), aPL = frag64(PaccL, 16*w, kk, lane);
      bf16x8 aBH = frag64(BaccH, 16*w, kk, lane), aBL = frag64(BaccL, 16*w, kk, lane);
      #pragma unroll
      for (int it = 0; it < 4; ++it){
        bf16x8 bH = frag64(PcH, 16*it, kk, lane), bL = frag64(PcL, 16*it, kk, lane);
        nP[it] = mfma16x16x32(aPH, bH, nP[it]);
        nP[it] = mfma16x16x32(aPH, bL, nP[it]);
        nP[it] = mfma16x16x32(aPL, bH, nP[it]);
        nB[it] = mfma16x16x32(aBH, bH, nB[it]);
        nB[it] = mfma16x16x32(aBH, bL, nB[it]);
        nB[it] = mfma16x16x32(aBL, bH, nB[it]);
      }
    }
    #pragma unroll
    for (int it = 0; it < 4; ++it)
      #pragma unroll
      for (int r = 0; r < 4; ++r){
        int row = 16*w + (lane>>4)*4 + r, col = 16*it + (lane&15);
        Pr[it][r] = nP[it][r];
        Br[it][r] = nB[it][r] + (float)BcS[row*64 + col];
      }
  }
  const size_t sb = (chain*8 + seg)*4096;
  #pragma unroll
  for (int it = 0; it < 4; ++it)
    #pragma unroll
    for (int r = 0; r < 4; ++r){
      int row = 16*w + (lane>>4)*4 + r, col = 16*it + (lane&15);
      PsegT[sb + (size_t)col*64 + row] = Pr[it][r];   // transposed (B-operand layout)
      BsegF[sb + (size_t)row*64 + col] = Br[it][r];   // natural
    }
}

// ---------------------------------------------------------------- K4b: segment-level scan (32 blocks, 8 steps)
__global__ __launch_bounds__(256) void k_phaseB2(const float* __restrict__ PsegT, const float* __restrict__ BsegF,
                                                 float* __restrict__ S0g){
  __shared__ bf16 Sh[4096], Sl[4096], Ph[4096], Pl[4096];
  __shared__ float Bf[4096];
  const int tid = threadIdx.x, lane = tid & 63, w = tid >> 6;
  const size_t bid = blockIdx.x;
  f32x4 Sr[4];
  #pragma unroll
  for (int it = 0; it < 4; ++it) Sr[it] = f32x4_zero();
  for (int seg = 0; seg < 8; ++seg){
    const size_t sb  = (bid*8 + seg)*4096;
    const size_t s0b = (bid*64 + (size_t)seg*8)*4096;
    #pragma unroll
    for (int it = 0; it < 4; ++it)
      #pragma unroll
      for (int r = 0; r < 4; ++r){
        int row = 16*w + (lane>>4)*4 + r, col = 16*it + (lane&15);
        S0g[s0b + (size_t)row*64 + col] = Sr[it][r];
        bf2 sp = split2(Sr[it][r]); Sh[row*64+col] = sp.h; Sl[row*64+col] = sp.l;
      }
    __syncthreads();
    for (int j = tid; j < 1024; j += 256){
      float4 pv = ((const float4*)(PsegT + sb))[j];
      bf16x4 ph, pl;
      bf2 u0 = split2(pv.x); ph[0]=u0.h; pl[0]=u0.l;
      bf2 u1 = split2(pv.y); ph[1]=u1.h; pl[1]=u1.l;
      bf2 u2 = split2(pv.z); ph[2]=u2.h; pl[2]=u2.l;
      bf2 u3 = split2(pv.w); ph[3]=u3.h; pl[3]=u3.l;
      ((bf16x4*)Ph)[j] = ph; ((bf16x4*)Pl)[j] = pl;
      ((float4*)Bf)[j] = ((const float4*)(BsegF + sb))[j];
    }
    __syncthreads();
    f32x4 nS[4];
    #pragma unroll
    for (int it = 0; it < 4; ++it) nS[it] = f32x4_zero();
    #pragma unroll
    for (int kk = 0; kk < 2; ++kk){
      bf16x8 aH = frag64(Sh, 16*w, kk, lane), aL = frag64(Sl, 16*w, kk, lane);
      #pragma unroll
      for (int it = 0; it < 4; ++it){
        bf16x8 bH = frag64(Ph, 16*it, kk, lane), bL = frag64(Pl, 16*it, kk, lane);
        nS[it] = mfma16x16x32(aH, bH, nS[it]);
        nS[it] = mfma16x16x32(aH, bL, nS[it]);
        nS[it] = mfma16x16x32(aL, bH, nS[it]);
      }
    }
    #pragma unroll
    for (int it = 0; it < 4; ++it)
      #pragma unroll
      for (int r = 0; r < 4; ++r){
        int row = 16*w + (lane>>4)*4 + r, col = 16*it + (lane&15);
        Sr[it][r] = nS[it][r] + Bf[row*64 + col];
      }
  }
}

// ---------------------------------------------------------------- K4c: within-segment replay (256 blocks, 7 steps)
__global__ __launch_bounds__(256) void k_phaseB3(const uint32_t* __restrict__ Pg,
                                                 const bf16* __restrict__ Bg,
                                                 float* __restrict__ S0g){
  __shared__ bf16 Sh[4096], Sl[4096], Ph[4096], Pl[4096];
  __shared__ bf16 BcS[4096];
  const int tid = threadIdx.x, lane = tid & 63, w = tid >> 6;
  const int seg = blockIdx.x;
  const size_t chain = blockIdx.y;
  const size_t segbase = chain*64 + (size_t)seg*8;
  f32x4 Sr[4];
  #pragma unroll
  for (int it = 0; it < 4; ++it)
    #pragma unroll
    for (int r = 0; r < 4; ++r){
      int row = 16*w + (lane>>4)*4 + r, col = 16*it + (lane&15);
      Sr[it][r] = S0g[segbase*4096 + (size_t)row*64 + col];
    }
  for (int i = 0; i < 7; ++i){
    const size_t cb = (segbase + i)*4096;
    #pragma unroll
    for (int it = 0; it < 4; ++it)
      #pragma unroll
      for (int r = 0; r < 4; ++r){
        int row = 16*w + (lane>>4)*4 + r, col = 16*it + (lane&15);
        bf2 sp = split2(Sr[it][r]); Sh[row*64+col] = sp.h; Sl[row*64+col] = sp.l;
      }
    __syncthreads();
    for (int j = tid; j < 1024; j += 256){
      uint4 p = ((const uint4*)(Pg + cb))[j];
      uint2 hh, ll;
      hh.x = (p.x & 0xFFFFu) | (p.y << 16);
      ll.x = (p.x >> 16)     | (p.y & 0xFFFF0000u);
      hh.y = (p.z & 0xFFFFu) | (p.w << 16);
      ll.y = (p.z >> 16)     | (p.w & 0xFFFF0000u);
      ((uint2*)Ph)[j] = hh;
      ((uint2*)Pl)[j] = ll;
    }
    for (int j = tid; j < 512; j += 256)
      ((uint4*)BcS)[j] = ((const uint4*)(Bg + cb))[j];
    __syncthreads();
    f32x4 nS[4];
    #pragma unroll
    for (int it = 0; it < 4; ++it) nS[it] = f32x4_zero();
    #pragma unroll
    for (int kk = 0; kk < 2; ++kk){
      bf16x8 aH = frag64(Sh, 16*w, kk, lane), aL = frag64(Sl, 16*w, kk, lane);
      #pragma unroll
      for (int it = 0; it < 4; ++it){
        bf16x8 bH = frag64(Ph, 16*it, kk, lane), bL = frag64(Pl, 16*it, kk, lane);
        nS[it] = mfma16x16x32(aH, bH, nS[it]);
        nS[it] = mfma16x16x32(aH, bL, nS[it]);
        nS[it] = mfma16x16x32(aL, bH, nS[it]);
      }
    }
    const size_t outb = (segbase + i + 1)*4096;
    #pragma unroll
    for (int it = 0; it < 4; ++it)
      #pragma unroll
      for (int r = 0; r < 4; ++r){
        int row = 16*w + (lane>>4)*4 + r, col = 16*it + (lane&15);
        float v = nS[it][r] + (float)BcS[row*64 + col];
        Sr[it][r] = v;
        S0g[outb + (size_t)row*64 + col] = v;
      }
  }
}

// ---------------------------------------------------------------- K5: phase C, outputs + fused RMSNorm/gate (2048 blocks)
__global__ __launch_bounds__(256, 2) void k_phaseC(
    const bf16* __restrict__ qhp, const bf16* __restrict__ qlp,
    const bf16* __restrict__ khp, const bf16* __restrict__ klp,
    const bf16* __restrict__ gf, const float* __restrict__ logA,
    const float* __restrict__ S0g, const bf16* __restrict__ Wg, const bf16* __restrict__ Dg,
    const float* __restrict__ rms_w, bf16* __restrict__ yh, bf16* __restrict__ yl){
  __shared__ bf16 Qh[4096], Ql[4096], Kh[4096], Klo[4096];
  __shared__ bf16 Wl_[4096], Dl_[4096];
  __shared__ bf16 S0h[4096], S0l[4096];
  __shared__ bf16 AAg[4096];
  __shared__ bf16 BDt[4096];
  const int tid = threadIdx.x, lane = tid & 63, w = tid >> 6;
  const int c = blockIdx.x, h = blockIdx.y, b = blockIdx.z;
  const size_t tokbase = (size_t)b*4096 + (size_t)c*64;
  const size_t cbase = ((size_t)((b*16 + h)*64 + c)) * 4096;

  { // async stage Q/K (hi/lo) + Wg/Dg with pre-swizzled source
    const int chunk = tid & 7, r0 = tid >> 3;   // r0 0..31; wave w rows 8w..8w+7 per round
    #pragma unroll
    for (int rr = 0; rr < 2; ++rr){
      const int row = 32*rr + r0;
      const int dbase = (32*rr + 8*w)*64;
      const size_t g = (tokbase + row)*1024 + (size_t)h*64 + 8*(chunk ^ (row & 7));
      GLD_LDS16(&qhp[g], &Qh[dbase]);
      if (qlp) GLD_LDS16(&qlp[g], &Ql[dbase]);
      GLD_LDS16(&khp[g], &Kh[dbase]);
      if (klp) GLD_LDS16(&klp[g], &Klo[dbase]);
      const size_t gg = cbase + (size_t)row*64 + 8*(chunk ^ (row & 7));
      GLD_LDS16(&Wg[gg], &Wl_[dbase]);
      GLD_LDS16(&Dg[gg], &Dl_[dbase]);
    }
    if (!qlp){
      uint4 z4; z4.x=0; z4.y=0; z4.z=0; z4.w=0;
      for (int z = tid; z < 512; z += 256){ ((uint4*)Ql)[z] = z4; ((uint4*)Klo)[z] = z4; }
    }
  }
  for (int i = tid; i < 1024; i += 256){
    float4 v = ((const float4*)(S0g + cbase))[i];
    bf16x4 sh, sl;
    bf2 t0 = split2(v.x); sh[0]=t0.h; sl[0]=t0.l;
    bf2 t1 = split2(v.y); sh[1]=t1.h; sl[1]=t1.l;
    bf2 t2 = split2(v.z); sh[2]=t2.h; sl[2]=t2.l;
    bf2 t3 = split2(v.w); sh[3]=t3.h; sl[3]=t3.l;
    int t = i >> 4, off = ((i&15)*4) ^ ((t&7)<<3);
    *(bf16x4*)&S0h[t*64 + off] = sh;
    *(bf16x4*)&S0l[t*64 + off] = sl;
  }
  // per-wave redundant lg cumsum
  float la = logA[(tokbase + lane)*16 + h];
  #pragma unroll
  for (int dlt = 1; dlt < 64; dlt <<= 1){
    float o = __shfl_up(la, dlt);
    if (lane >= dlt) la += o;
  }
  __syncthreads();

  { // AAg = mask_incl(Gamma .* QK^T), 3-product
    const int t0 = 16*w;
    #pragma unroll
    for (int tu = 0; tu < 4; ++tu){
      f32x4 accm = f32x4_zero();
      #pragma unroll
      for (int kk = 0; kk < 2; ++kk){
        bf16x8 aH = fragSwz(Qh,  t0,    kk, lane);
        bf16x8 aL = fragSwz(Ql,  t0,    kk, lane);
        bf16x8 bH = fragSwz(Kh,  16*tu, kk, lane);
        bf16x8 bL = fragSwz(Klo, 16*tu, kk, lane);
        accm = mfma16x16x32(aH, bH, accm);
        accm = mfma16x16x32(aH, bL, accm);
        accm = mfma16x16x32(aL, bH, accm);
      }
      #pragma unroll
      for (int r = 0; r < 4; ++r){
        int row = t0 + (lane>>4)*4 + r, col = 16*tu + (lane&15);
        float lgr = __shfl(la, row), lgc = __shfl(la, col);
        float v = (col <= row) ? accm[r]*__expf(lgr - lgc) : 0.f;
        AAg[row*64 + (col ^ ((row&7)<<3))] = (bf16)v;
      }
    }
  }
  { // BDt[i][tau] = Dloc[tau][i] - (S0 W_hat^T)[i][tau]
    const int i0 = 16*w;
    #pragma unroll
    for (int tu = 0; tu < 4; ++tu){
      f32x4 accm = f32x4_zero();
      #pragma unroll
      for (int kk = 0; kk < 2; ++kk){
        bf16x8 aH = fragSwz(S0h, i0,    kk, lane);
        bf16x8 aL = fragSwz(S0l, i0,    kk, lane);
        bf16x8 bb = fragSwz(Wl_, 16*tu, kk, lane);
        accm = mfma16x16x32(aH, bb, accm);
        accm = mfma16x16x32(aL, bb, accm);
      }
      #pragma unroll
      for (int r = 0; r < 4; ++r){
        int row = i0 + (lane>>4)*4 + r, col = 16*tu + (lane&15);
        float v = (float)Dl_[col*64 + (row ^ ((col&7)<<3))] - accm[r];
        BDt[row*64 + (col ^ ((row&7)<<3))] = (bf16)v;
      }
    }
  }
  __syncthreads();
  for (int i = tid; i < 4096; i += 256){
    int t = i >> 6;                              // uniform per wave per iteration
    float gq = __expf(__shfl(la, t));
    float v = gq * ((float)Qh[i] + (float)Ql[i]);  // swizzle is within-row: row scale layout-agnostic
    bf2 sp = split2(v);
    Qh[i] = sp.h; Ql[i] = sp.l;
  }
  __syncthreads();
  {
    const int t0 = 16*w;
    f32x4 o_acc[4];
    #pragma unroll
    for (int it = 0; it < 4; ++it) o_acc[it] = f32x4_zero();
    #pragma unroll
    for (int kk = 0; kk < 2; ++kk){
      bf16x8 aQh = fragSwz(Qh, t0, kk, lane);
      bf16x8 aQl = fragSwz(Ql, t0, kk, lane);
      bf16x8 aA  = fragSwz(AAg, t0, kk, lane);
      #pragma unroll
      for (int it = 0; it < 4; ++it){
        bf16x8 bSh = fragSwz(S0h, 16*it, kk, lane);
        bf16x8 bSl = fragSwz(S0l, 16*it, kk, lane);
        bf16x8 bD  = fragSwz(BDt, 16*it, kk, lane);
        f32x4 t = o_acc[it];
        t = mfma16x16x32(aQh, bSh, t);
        t = mfma16x16x32(aQh, bSl, t);
        t = mfma16x16x32(aQl, bSh, t);
        t = mfma16x16x32(aA,  bD,  t);
        o_acc[it] = t;
      }
    }
    float rw[4];
    #pragma unroll
    for (int it = 0; it < 4; ++it) rw[it] = rms_w[16*it + (lane&15)];
    #pragma unroll
    for (int r = 0; r < 4; ++r){
      float ss = 0.f;
      #pragma unroll
      for (int it = 0; it < 4; ++it) ss += o_acc[it][r]*o_acc[it][r];
      ss += __shfl_xor(ss, 1); ss += __shfl_xor(ss, 2);
      ss += __shfl_xor(ss, 4); ss += __shfl_xor(ss, 8);
      const float scale = rsqrtf(ss*(1.f/64.f) + 1e-6f);
      const int row = t0 + (lane>>4)*4 + r;
      const size_t tok = tokbase + row;
      #pragma unroll
      for (int it = 0; it < 4; ++it){
        const int col = 16*it + (lane&15);
        float g = (float)gf[tok*1024 + h*64 + col];
        float sg = g / (1.f + __expf(-g));
        float v = o_acc[it][r]*scale*rw[it]*sg;
        bf2 sp = split2(v);
        yh[tok*1024 + h*64 + col] = sp.h;
        yl[tok*1024 + h*64 + col] = sp.l;
      }
    }
  }
}

// ---------------------------------------------------------------- launcher
extern "C" void kernel_launch(void* const* d_in, const int* in_sizes, int n_in,
                              void* d_out, int out_size, void* d_ws, size_t ws_size,
                              hipStream_t stream){
  const float* x     = (const float*)d_in[0];
  const float* Wq    = (const float*)d_in[1];
  const float* Wk    = (const float*)d_in[2];
  const float* Wv    = (const float*)d_in[3];
  const float* Wa    = (const float*)d_in[4];
  const float* Wb    = (const float*)d_in[5];
  const float* A_log = (const float*)d_in[6];
  const float* dt_b  = (const float*)d_in[7];
  const float* Wgt   = (const float*)d_in[8];
  const float* Wo    = (const float*)d_in[9];
  const float* rms_w = (const float*)d_in[10];

  const bool BIG = ws_size >= (size_t)215000000;

  char* ws = (char*)d_ws;
  size_t off = 0;
  auto alloc = [&](size_t bytes)->char*{
    char* p = ws + off;
    off += (bytes + 255) & ~(size_t)255;
    return p;
  };
  const size_t PLANE = (size_t)8192*1024*2;   // bf16 activation plane (16 MiB)
  const size_t WPL   = (size_t)1024*1024*2;   // bf16 weight plane (2 MiB)
  bf16* xh  = (bf16*)alloc(PLANE);            // region also hosts packed Pg (A->B3), then yh
  bf16* xl  = (bf16*)alloc(PLANE);            // (xh+xl contiguous: PLANE is 256-aligned)
  bf16* wqh = (bf16*)alloc(WPL); bf16* wql = (bf16*)alloc(WPL);   // wqh..wgl also hosts Bg
  bf16* wkh = (bf16*)alloc(WPL); bf16* wkl = (bf16*)alloc(WPL);
  bf16* wvh = (bf16*)alloc(WPL); bf16* wvl = (bf16*)alloc(WPL);
  bf16* wgh = (bf16*)alloc(WPL); bf16* wgl = (bf16*)alloc(WPL);
  bf16* woh = (bf16*)alloc(WPL); bf16* wol = (bf16*)alloc(WPL);
  bf16* WabTh = (bf16*)alloc((size_t)32*1024*2);
  bf16* WabTl = (bf16*)alloc((size_t)32*1024*2);
  // q/k as hi/lo bf16 split planes (hi-only in SMALL)
  bf16* qh = nullptr; bf16* ql = nullptr;
  bf16* kh = nullptr; bf16* kl = nullptr;
  if (BIG){
    qh = (bf16*)alloc(PLANE); ql = (bf16*)alloc(PLANE);
    kh = (bf16*)alloc(PLANE); kl = (bf16*)alloc(PLANE);
  } else {
    qh = (bf16*)alloc(PLANE);
    kh = (bf16*)alloc(PLANE);
  }
  float* vf  = (float*)alloc((size_t)8192*1024*4);  // dead after phase A -> hosts S0g
  bf16* gfb  = (bf16*)alloc(PLANE);
  float* logA  = (float*)alloc((size_t)8192*16*4);
  float* betap = (float*)alloc((size_t)8192*16*4);
  bf16* Wg  = (bf16*)alloc((size_t)2048*4096*2);
  bf16* Dg  = (bf16*)alloc((size_t)2048*4096*2);
  uint32_t* Pg = (uint32_t*)xh;       // packed hi|lo P plane, 33.5 MB spanning xh+xl
  float* S0g = vf;                    // 33.5 MiB fp32 (vf dead after phase A)
  bf16* Bg   = wqh;                   // 16 MiB bf16 (projection weights dead)
  float* PsegT = (float*)d_out;       // 4 MiB scratch in d_out (overwritten by final GEMM)
  float* BsegF = (float*)d_out + 1048576;  // next 4 MiB
  bf16* yh = xh;                      // phase C outputs (Pg dead after B3)
  bf16* yl = xl;

  k_cvt_x<<<8192, 256, 0, stream>>>(x, xh, xl, 2097152);
  k_transpose_w<<<dim3(32,32), 256, 0, stream>>>(Wq,  wqh, wql);
  k_transpose_w<<<dim3(32,32), 256, 0, stream>>>(Wk,  wkh, wkl);
  k_transpose_w<<<dim3(32,32), 256, 0, stream>>>(Wv,  wvh, wvl);
  k_transpose_w<<<dim3(32,32), 256, 0, stream>>>(Wgt, wgh, wgl);
  k_transpose_w<<<dim3(32,32), 256, 0, stream>>>(Wo,  woh, wol);
  k_transpose_ab<<<128, 256, 0, stream>>>(Wa, Wb, WabTh, WabTl);

  k_gemm1<1><<<dim3(64,8), 256, 0, stream>>>(xh, wqh, qh, nullptr, ql);  // ql may be null (hi-only)
  k_gemm1<2><<<dim3(64,8), 256, 0, stream>>>(xh, wkh, kh, nullptr, kl);
  k_gemm1<0><<<dim3(64,8), 256, 0, stream>>>(xh, wvh, nullptr, vf, nullptr);
  k_gemm1<0><<<dim3(64,8), 256, 0, stream>>>(xh, wgh, gfb, nullptr, nullptr);

  k_ab_gemm<<<256, 256, 0, stream>>>(xh, xl, WabTh, WabTl, A_log, dt_b, logA, betap);

  k_phaseA<<<dim3(64,16,2), 128, 0, stream>>>(kh, kl, vf, logA, betap, Wg, Dg, Pg, Bg);
  k_phaseB1<<<dim3(8,32), 256, 0, stream>>>(Pg, Bg, PsegT, BsegF);
  k_phaseB2<<<32, 256, 0, stream>>>(PsegT, BsegF, S0g);
  k_phaseB3<<<dim3(8,32), 256, 0, stream>>>(Pg, Bg, S0g);
  k_phaseC<<<dim3(64,16,2), 256, 0, stream>>>(qh, ql, kh, kl, gfb, logA, S0g, Wg, Dg, rms_w, yh, yl);

  k_gemm3<<<dim3(64,8), 256, 0, stream>>>(yh, yl, woh, wol, nullptr, (float*)d_out);
}

// Round 9
// 497.794 us; speedup vs baseline: 1.0303x; 1.0303x over previous
//
#include <hip/hip_runtime.h>
#include <cstdint>
#include <cstddef>

typedef __bf16 bf16;
typedef __bf16 bf16x4 __attribute__((ext_vector_type(4)));
typedef __bf16 bf16x8 __attribute__((ext_vector_type(8)));
typedef float  f32x4  __attribute__((ext_vector_type(4)));

#define GLD_LDS16(gp, lp) \
  __builtin_amdgcn_global_load_lds((__attribute__((address_space(1))) void*)(gp), \
                                   (__attribute__((address_space(3))) void*)(lp), 16, 0, 0)

__device__ __forceinline__ f32x4 f32x4_zero(){ f32x4 v; v[0]=0.f; v[1]=0.f; v[2]=0.f; v[3]=0.f; return v; }

__device__ __forceinline__ f32x4 mfma16x16x32(bf16x8 a, bf16x8 b, f32x4 c){
  return __builtin_amdgcn_mfma_f32_16x16x32_bf16(a, b, c, 0, 0, 0);
}
// fragment of a 64-col bf16 LDS array (stride 64), LINEAR layout (phaseB kernels)
__device__ __forceinline__ bf16x8 frag64(const bf16* base, int row0, int kk, int lane){
  return *(const bf16x8*)&base[(row0 + (lane&15))*64 + kk*32 + (lane>>4)*8];
}
// fragment of a 64-col bf16 LDS array with XOR bank-swizzle: elem ^= (row&7)<<3
__device__ __forceinline__ bf16x8 fragSwz(const bf16* base, int row0, int kk, int lane){
  const int row = row0 + (lane&15);
  const int off = (kk*32 + (lane>>4)*8) ^ ((row&7)<<3);
  return *(const bf16x8*)&base[row*64 + off];
}
struct bf2 { bf16 h, l; };
__device__ __forceinline__ bf2 split2(float v){
  bf2 r; r.h = (bf16)v; r.l = (bf16)(v - (float)r.h); return r;
}
// pack hi/lo split of v into one dword: bits(h) | bits(l)<<16
__device__ __forceinline__ uint32_t pack2(float v){
  bf2 s = split2(v);
  union { bf16 b; uint16_t u; } uh, ul;
  uh.b = s.h; ul.b = s.l;
  return (uint32_t)uh.u | ((uint32_t)ul.u << 16);
}

// ---------------------------------------------------------------- K0a: x -> hi/lo bf16 planes
__global__ __launch_bounds__(256) void k_cvt_x(const float* __restrict__ x,
                                               bf16* __restrict__ xh, bf16* __restrict__ xl, int n4){
  int i = blockIdx.x*256 + threadIdx.x;
  if (i < n4){
    float4 v = ((const float4*)x)[i];
    bf16x4 h, l;
    bf2 t0 = split2(v.x); h[0]=t0.h; l[0]=t0.l;
    bf2 t1 = split2(v.y); h[1]=t1.h; l[1]=t1.l;
    bf2 t2 = split2(v.z); h[2]=t2.h; l[2]=t2.l;
    bf2 t3 = split2(v.w); h[3]=t3.h; l[3]=t3.l;
    ((bf16x4*)xh)[i] = h;
    ((bf16x4*)xl)[i] = l;
  }
}

// ---------------------------------------------------------------- K0b: 5x W[k][n] -> Wt hi/lo [n][k], one launch
// dst planes contiguous: WtBase + z*2M elems = hi plane of matrix z, +1M = lo plane.
__global__ __launch_bounds__(256) void k_transpose_w5(const float* __restrict__ W0, const float* __restrict__ W1,
                                                      const float* __restrict__ W2, const float* __restrict__ W3,
                                                      const float* __restrict__ W4, bf16* __restrict__ WtBase){
  __shared__ float tile[32][33];
  const int z = blockIdx.z;
  const float* W = (z==0)?W0:(z==1)?W1:(z==2)?W2:(z==3)?W3:W4;
  bf16* Wth = WtBase + (size_t)z*2097152;
  bf16* Wtl = Wth + 1048576;
  const int k0 = blockIdx.x*32, n0 = blockIdx.y*32;
  const int r = threadIdx.x >> 3, c4 = (threadIdx.x & 7)*4;
  float4 v = *(const float4*)&W[(size_t)(k0+r)*1024 + n0 + c4];
  tile[r][c4+0]=v.x; tile[r][c4+1]=v.y; tile[r][c4+2]=v.z; tile[r][c4+3]=v.w;
  __syncthreads();
  bf16x4 h, l;
  bf2 t0 = split2(tile[c4+0][r]); h[0]=t0.h; l[0]=t0.l;
  bf2 t1 = split2(tile[c4+1][r]); h[1]=t1.h; l[1]=t1.l;
  bf2 t2 = split2(tile[c4+2][r]); h[2]=t2.h; l[2]=t2.l;
  bf2 t3 = split2(tile[c4+3][r]); h[3]=t3.h; l[3]=t3.l;
  *(bf16x4*)&Wth[(size_t)(n0+r)*1024 + k0 + c4] = h;
  *(bf16x4*)&Wtl[(size_t)(n0+r)*1024 + k0 + c4] = l;
}

// ---------------------------------------------------------------- K0c: Walpha/Wbeta [1024][16] -> WabT hi/lo bf16 [32][1024]
__global__ __launch_bounds__(256) void k_transpose_ab(const float* __restrict__ Wa, const float* __restrict__ Wb,
                                                      bf16* __restrict__ WabTh, bf16* __restrict__ WabTl){
  int p = blockIdx.x*256 + threadIdx.x;
  if (p < 32768){
    int o = p >> 10, k = p & 1023;
    float v = (o < 16) ? Wa[k*16 + o] : Wb[k*16 + (o-16)];
    bf2 s = split2(v);
    WabTh[p] = s.h;
    WabTl[p] = s.l;
  }
}

// ---------------------------------------------------------------- K1: split-bf16 MFMA GEMM (3-product), K=1024
__global__ __launch_bounds__(256) void k_gemm3(const bf16* __restrict__ Ah, const bf16* __restrict__ Al,
                                               const bf16* __restrict__ Bth, const bf16* __restrict__ Btl,
                                               bf16* __restrict__ Cb, float* __restrict__ Cf){
  __shared__ bf16 Ash[128*32], Asl[128*32];
  __shared__ bf16 Bsh[128*32], Bsl[128*32];
  const int tid = threadIdx.x, lane = tid & 63, w = tid >> 6;
  const int wm = w >> 1, wn = w & 1;
  const size_t m0 = (size_t)blockIdx.x * 128;
  const size_t n0 = (size_t)blockIdx.y * 128;
  f32x4 acc[4][4];
  #pragma unroll
  for (int i=0;i<4;++i)
    #pragma unroll
    for (int j=0;j<4;++j) acc[i][j] = f32x4_zero();

  for (int k0 = 0; k0 < 1024; k0 += 32){
    __syncthreads();
    #pragma unroll
    for (int j = 0; j < 2; ++j){
      const int rbase = 32*w + 16*j;
      const int r = rbase + (lane >> 2);
      const int kk = k0 + (lane & 3)*8;
      GLD_LDS16(&Ah [(m0 + r)*1024 + kk], &Ash[rbase*32]);
      GLD_LDS16(&Al [(m0 + r)*1024 + kk], &Asl[rbase*32]);
      GLD_LDS16(&Bth[(n0 + r)*1024 + kk], &Bsh[rbase*32]);
      GLD_LDS16(&Btl[(n0 + r)*1024 + kk], &Bsl[rbase*32]);
    }
    __syncthreads();
    bf16x8 ah[4], al[4], bh[4], bl[4];
    #pragma unroll
    for (int t=0;t<4;++t){
      ah[t] = *(const bf16x8*)&Ash[(64*wm + 16*t + (lane&15))*32 + (lane>>4)*8];
      al[t] = *(const bf16x8*)&Asl[(64*wm + 16*t + (lane&15))*32 + (lane>>4)*8];
      bh[t] = *(const bf16x8*)&Bsh[(64*wn + 16*t + (lane&15))*32 + (lane>>4)*8];
      bl[t] = *(const bf16x8*)&Bsl[(64*wn + 16*t + (lane&15))*32 + (lane>>4)*8];
    }
    #pragma unroll
    for (int i=0;i<4;++i)
      #pragma unroll
      for (int j=0;j<4;++j){
        f32x4 t = acc[i][j];
        t = mfma16x16x32(ah[i], bh[j], t);
        t = mfma16x16x32(ah[i], bl[j], t);
        t = mfma16x16x32(al[i], bh[j], t);
        acc[i][j] = t;
      }
  }
  #pragma unroll
  for (int i=0;i<4;++i)
    #pragma unroll
    for (int j=0;j<4;++j)
      #pragma unroll
      for (int r=0;r<4;++r){
        size_t row = m0 + 64*wm + 16*i + (lane>>4)*4 + r;
        size_t col = n0 + 64*wn + 16*j + (lane&15);
        float v = acc[i][j][r];
        if (Cf) Cf[row*1024 + col] = v;
        else    Cb[row*1024 + col] = (bf16)v;
      }
}

// ---------------------------------------------------------------- K1b: fused q/k/v/g projection GEMM, K=1024
// grid (64, 32): blockIdx.y>>3 selects matrix {0=q,1=k,2=v,3=g}; (y&7)*128 = n0.
// Weight hi planes contiguous at WtBase + which*2M elems. Epilogue per matrix:
// q: l2norm 0.125/||.||, split out (or hi-only); k: l2norm 1/||.||, split out;
// v: fp32 out; g: bf16 out. Replaces 4 separate launches (3 ramp/drain tails saved).
__global__ __launch_bounds__(256) void k_gemm_qkvg(const bf16* __restrict__ Ah,
    const bf16* __restrict__ WtBase,
    bf16* __restrict__ qh, bf16* __restrict__ ql,
    bf16* __restrict__ kh, bf16* __restrict__ kl,
    float* __restrict__ vf, bf16* __restrict__ gfb){
  __shared__ bf16 Ash[128*32];
  __shared__ bf16 Bsh[128*32];
  const int tid = threadIdx.x, lane = tid & 63, w = tid >> 6;
  const int wm = w >> 1, wn = w & 1;
  const int which = blockIdx.y >> 3;
  const bf16* Bth = WtBase + (size_t)which * 2097152;
  const size_t m0 = (size_t)blockIdx.x * 128;
  const size_t n0 = (size_t)(blockIdx.y & 7) * 128;
  f32x4 acc[4][4];
  #pragma unroll
  for (int i=0;i<4;++i)
    #pragma unroll
    for (int j=0;j<4;++j) acc[i][j] = f32x4_zero();

  for (int k0 = 0; k0 < 1024; k0 += 32){
    __syncthreads();
    #pragma unroll
    for (int j = 0; j < 2; ++j){
      const int rbase = 32*w + 16*j;
      const int r = rbase + (lane >> 2);
      const int kk = k0 + (lane & 3)*8;
      GLD_LDS16(&Ah [(m0 + r)*1024 + kk], &Ash[rbase*32]);
      GLD_LDS16(&Bth[(n0 + r)*1024 + kk], &Bsh[rbase*32]);
    }
    __syncthreads();
    bf16x8 ah[4], bh[4];
    #pragma unroll
    for (int t=0;t<4;++t){
      ah[t] = *(const bf16x8*)&Ash[(64*wm + 16*t + (lane&15))*32 + (lane>>4)*8];
      bh[t] = *(const bf16x8*)&Bsh[(64*wn + 16*t + (lane&15))*32 + (lane>>4)*8];
    }
    #pragma unroll
    for (int i=0;i<4;++i)
      #pragma unroll
      for (int j=0;j<4;++j)
        acc[i][j] = mfma16x16x32(ah[i], bh[j], acc[i][j]);
  }
  #pragma unroll
  for (int i=0;i<4;++i)
    #pragma unroll
    for (int r=0;r<4;++r){
      float sc = 1.f;
      if (which <= 1){   // fused head l2norm (q also /8)
        float ss = 0.f;
        #pragma unroll
        for (int j=0;j<4;++j) ss += acc[i][j][r]*acc[i][j][r];
        ss += __shfl_xor(ss, 1); ss += __shfl_xor(ss, 2);
        ss += __shfl_xor(ss, 4); ss += __shfl_xor(ss, 8);
        sc = ((which==0) ? 0.125f : 1.0f) / fmaxf(sqrtf(ss), 1e-12f);
      }
      #pragma unroll
      for (int j=0;j<4;++j){
        size_t row = m0 + 64*wm + 16*i + (lane>>4)*4 + r;
        size_t col = n0 + 64*wn + 16*j + (lane&15);
        float v = acc[i][j][r]*sc;
        if (which <= 1){
          bf16* Ch = which ? kh : qh;
          bf16* Cl = which ? kl : ql;
          if (Cl){ bf2 sp = split2(v); Ch[row*1024 + col] = sp.h; Cl[row*1024 + col] = sp.l; }
          else   { Ch[row*1024 + col] = (bf16)v; }
        } else if (which == 2){
          vf[row*1024 + col] = v;
        } else {
          gfb[row*1024 + col] = (bf16)v;
        }
      }
    }
}

// ---------------------------------------------------------------- K2: alpha/beta projections as split-bf16 MFMA GEMM
__global__ __launch_bounds__(256) void k_ab_gemm(const bf16* __restrict__ xh, const bf16* __restrict__ xl,
    const bf16* __restrict__ WabTh, const bf16* __restrict__ WabTl,
    const float* __restrict__ A_log, const float* __restrict__ dt_bias,
    float* __restrict__ logA, float* __restrict__ betap){
  __shared__ bf16 Ash[2][2048], Asl[2][2048];   // 32 rows x 64 k per buffer
  const int tid = threadIdx.x, lane = tid & 63, w = tid >> 6;
  const int mt = w >> 1, nt = w & 1;
  const size_t m0 = (size_t)blockIdx.x * 32;
  const int srow = tid >> 3;
  const int scol = 8*((tid & 7) ^ (srow & 7));
  const size_t sg = (m0 + srow)*1024 + scol;

  f32x4 acc = f32x4_zero();
  GLD_LDS16(&xh[sg], &Ash[0][w*512]);
  GLD_LDS16(&xl[sg], &Asl[0][w*512]);
  for (int s = 0; s < 16; ++s){
    const int cur = s & 1;
    __syncthreads();                    // implicit vmcnt(0): buf[cur] staged
    if (s + 1 < 16){
      const size_t g = sg + (size_t)(s+1)*64;
      GLD_LDS16(&xh[g], &Ash[cur^1][w*512]);
      GLD_LDS16(&xl[g], &Asl[cur^1][w*512]);
    }
    const int k0 = s*64;
    #pragma unroll
    for (int kk = 0; kk < 2; ++kk){
      bf16x8 aH = fragSwz(Ash[cur], 16*mt, kk, lane);
      bf16x8 aL = fragSwz(Asl[cur], 16*mt, kk, lane);
      const size_t bo = (size_t)(16*nt + (lane&15))*1024 + k0 + kk*32 + (lane>>4)*8;
      bf16x8 bH = *(const bf16x8*)&WabTh[bo];
      bf16x8 bL = *(const bf16x8*)&WabTl[bo];
      acc = mfma16x16x32(aH, bH, acc);
      acc = mfma16x16x32(aH, bL, acc);
      acc = mfma16x16x32(aL, bH, acc);
    }
  }
  const int col = lane & 15;
  #pragma unroll
  for (int r = 0; r < 4; ++r){
    const size_t row = m0 + 16*mt + (lane>>4)*4 + r;
    float v = acc[r];
    if (nt == 0){
      float z = v + dt_bias[col];
      float dt = (z > 20.f) ? z : log1pf(expf(z));
      logA[row*16 + col] = -expf(A_log[col]) * dt;   // log(alpha_t)
    } else {
      betap[row*16 + col] = 1.f/(1.f + expf(-v));    // beta_t
    }
  }
}

// ---------------------------------------------------------------- K3: phase A (2048 blocks, 128 thr)
// LDS 32768 -> 5 blocks/CU; (128,4) caps VGPR 128 (84 actual). K staged via GLD (pre-swizzled
// source). beta folded into E/RHS. Serial diag solve (r5 form). P output: PACKED hi|lo dwords
// -> 64 coalesced dword stores; B1/B3 de-interleave with bit ops.
__global__ __launch_bounds__(128, 4) void k_phaseA(const bf16* __restrict__ khp, const bf16* __restrict__ klp,
    const float* __restrict__ vf, const float* __restrict__ logA, const float* __restrict__ betap,
    bf16* __restrict__ Wg, bf16* __restrict__ Dg,
    uint32_t* __restrict__ Pg, bf16* __restrict__ Bg){
  __shared__ bf16  Kh[4096], Kl_[4096];   // 8 KiB + 8 KiB
  __shared__ float Ef[4096];              // 16 KiB; row 0 = lg cumsum
  bf16* DT  = Kh;                         // overlay: Dsol^T (after KtT build)
  bf16* WT  = Kl_;                        // overlay: Wsol^T
  bf16* KtT = (bf16*)&Ef[2048];           // overlay: K_til^T (Ef rows 32..63, after solve)
  const int tid = threadIdx.x, lane = tid & 63, wid = tid >> 6;
  const int c = blockIdx.x, h = blockIdx.y, b = blockIdx.z;
  const size_t tokbase = (size_t)b*4096 + (size_t)c*64;
  const size_t cbase = ((size_t)((b*16 + h)*64 + c)) * 4096;

  { // async stage K tile (hi/lo) with pre-swizzled source
    const int chunk = tid & 7, r0 = tid >> 3;       // r0: wave0 0..7, wave1 8..15
    #pragma unroll
    for (int rr = 0; rr < 4; ++rr){
      const int row = 16*rr + r0;
      const size_t g = (tokbase + row)*1024 + (size_t)h*64 + 8*(chunk ^ (row & 7));
      GLD_LDS16(&khp[g], &Kh[(16*rr + 8*wid)*64]);
      if (klp) GLD_LDS16(&klp[g], &Kl_[(16*rr + 8*wid)*64]);
    }
    if (!klp){
      uint4 z4; z4.x=0; z4.y=0; z4.z=0; z4.w=0;
      for (int z = tid; z < 512; z += 128) ((uint4*)Kl_)[z] = z4;
    }
  }
  const float bet = betap[(tokbase + lane)*16 + h];   // per-lane beta_t, t = lane
  if (tid < 64){
    float la = logA[(tokbase + tid)*16 + h];
    #pragma unroll
    for (int dlt = 1; dlt < 64; dlt <<= 1){
      float o = __shfl_up(la, dlt);
      if (lane >= dlt) la += o;
    }
    Ef[tid] = la;                // lg cumsum in E row 0 (row 0 never read by solve)
  }
  __syncthreads();               // GLD staged + lg ready

  // E~[t][tau] = beta_t * (gamma_t/gamma_tau)*(k_t . k_tau), strictly lower; else 0
  #pragma unroll
  for (int tt = 0; tt < 2; ++tt){
    const int t0 = 32*wid + 16*tt;
    #pragma unroll
    for (int tu = 0; tu < 4; ++tu){
      f32x4 accm = f32x4_zero();
      #pragma unroll
      for (int kk = 0; kk < 2; ++kk){
        bf16x8 aH = fragSwz(Kh,  t0,    kk, lane);
        bf16x8 aL = fragSwz(Kl_, t0,    kk, lane);
        bf16x8 bH = fragSwz(Kh,  16*tu, kk, lane);
        bf16x8 bL = fragSwz(Kl_, 16*tu, kk, lane);
        accm = mfma16x16x32(aH, bH, accm);
        accm = mfma16x16x32(aH, bL, accm);
        accm = mfma16x16x32(aL, bH, accm);
      }
      #pragma unroll
      for (int r = 0; r < 4; ++r){
        int row = t0 + (lane>>4)*4 + r, col = 16*tu + (lane&15);
        float bR = __shfl(bet, row);   // beta folded into E row
        float ev = (col < row) ? accm[r]*__expf(Ef[row] - Ef[col])*bR : 0.f;
        if (row > 0) Ef[row*64 + col] = ev;   // row 0 never read; keeps lg intact
      }
    }
  }
  __syncthreads();   // E complete (both waves) before solve reads

  // right-looking blocked forward substitution, beta pre-folded (serial diag -- r5 form)
  float d[64];
  {
    if (wid == 0){
      #pragma unroll
      for (int t = 0; t < 64; ++t)
        d[t] = __shfl(bet, t) * vf[(tokbase + t)*1024 + h*64 + lane];
    } else {
      #pragma unroll
      for (int t = 0; t < 64; ++t){
        int ks = lane ^ ((t&7)<<3);
        d[t] = __shfl(bet, t) * __expf(Ef[t]) * ((float)Kh[t*64 + ks] + (float)Kl_[t*64 + ks]);
      }
    }
    #pragma unroll
    for (int bi = 0; bi < 4; ++bi){
      // diagonal 16x16 unit-lower solve (serial accumulate)
      #pragma unroll
      for (int tt = 0; tt < 16; ++tt){
        const int t = 16*bi + tt;
        float s = 0.f;
        #pragma unroll
        for (int j = 0; j < 16; ++j)
          if (j < tt) s += Ef[t*64 + 16*bi + j] * d[16*bi + j];
        d[t] = d[t] - s;
      }
      // trailing rank-16 update of all later blocks (independent per t)
      #pragma unroll
      for (int b2 = bi + 1; b2 < 4; ++b2)
        #pragma unroll
        for (int tt = 0; tt < 16; ++tt){
          const int t = 16*b2 + tt;
          float a0=0.f,a1=0.f,a2=0.f,a3=0.f;
          #pragma unroll
          for (int q = 0; q < 4; ++q){
            float4 e = *(const float4*)&Ef[t*64 + 16*bi + q*4];
            a0 += e.x * d[16*bi + q*4 + 0];
            a1 += e.y * d[16*bi + q*4 + 1];
            a2 += e.z * d[16*bi + q*4 + 2];
            a3 += e.w * d[16*bi + q*4 + 3];
          }
          d[t] -= (a0+a1)+(a2+a3);
        }
    }
  }
  __syncthreads();   // all Ef/Kh/Kl solve reads done

  // K_til^T[j][t] = (gamma_L/gamma_t) * k[t][j]  (built AFTER solve, into Ef rows 32..63)
  {
    const float gsc = __expf(Ef[63] - Ef[lane]);   // t == lane for the stride-128 loop
    for (int i = tid; i < 4096; i += 128){
      int t = lane, j = i >> 6;
      int ks = j ^ ((t&7)<<3);
      float kv = (float)Kh[t*64 + ks] + (float)Kl_[t*64 + ks];
      KtT[j*64 + (t ^ ((j&7)<<3))] = (bf16)(gsc * kv);
    }
  }
  __syncthreads();   // KtT built; Kh/Kl_ now dead -> DT/WT overlay safe

  const float gL = __expf(Ef[63]);   // Ef row 0 intact (KtT occupies rows 32..63 only)
  {
    bf16* myT = wid ? WT : DT;
    #pragma unroll
    for (int s4 = 0; s4 < 16; ++s4){
      bf16x4 v4;
      v4[0]=(bf16)d[s4*4+0]; v4[1]=(bf16)d[s4*4+1];
      v4[2]=(bf16)d[s4*4+2]; v4[3]=(bf16)d[s4*4+3];
      *(bf16x4*)&myT[lane*64 + ((s4*4) ^ ((lane&7)<<3))] = v4;
    }
    bf16* myG = wid ? Wg : Dg;
    #pragma unroll
    for (int t = 0; t < 64; ++t)
      myG[cbase + (size_t)t*64 + lane] = (bf16)d[t];
  }
  __syncthreads();

  // P^T[j][i] = gamma_L*I - sum_t K_til[t][j]*Wsol[t][i]  (wave0, MFMA, packed hi|lo dword out)
  // B[i][j]   =              sum_t Dsol[t][i]*K_til[t][j]  (wave1, MFMA, bf16 out)
  if (wid == 0){
    #pragma unroll
    for (int tj = 0; tj < 4; ++tj)
      #pragma unroll
      for (int ti = 0; ti < 4; ++ti){
        f32x4 acc = f32x4_zero();
        #pragma unroll
        for (int kk = 0; kk < 2; ++kk)
          acc = mfma16x16x32(fragSwz(KtT, 16*tj, kk, lane), fragSwz(WT, 16*ti, kk, lane), acc);
        #pragma unroll
        for (int r = 0; r < 4; ++r){
          int row = 16*tj + (lane>>4)*4 + r, col = 16*ti + (lane&15);
          float v = ((row == col) ? gL : 0.f) - acc[r];
          Pg[cbase + (size_t)row*64 + col] = pack2(v);
        }
      }
  } else {
    #pragma unroll
    for (int ti = 0; ti < 4; ++ti)
      #pragma unroll
      for (int tj = 0; tj < 4; ++tj){
        f32x4 acc = f32x4_zero();
        #pragma unroll
        for (int kk = 0; kk < 2; ++kk)
          acc = mfma16x16x32(fragSwz(DT, 16*ti, kk, lane), fragSwz(KtT, 16*tj, kk, lane), acc);
        #pragma unroll
        for (int r = 0; r < 4; ++r){
          int row = 16*ti + (lane>>4)*4 + r, col = 16*tj + (lane&15);
          Bg[cbase + (size_t)row*64 + col] = (bf16)acc[r];
        }
      }
  }
}

// ---------------------------------------------------------------- K4a: segment composition (256 blocks: 8 seg x 32 chains)
// P arrives as packed hi|lo dwords -> de-interleave with bit ops (no fp split2)
__global__ __launch_bounds__(256) void k_phaseB1(const uint32_t* __restrict__ Pg,
                                                 const bf16* __restrict__ Bg,
                                                 float* __restrict__ PsegT, float* __restrict__ BsegF){
  __shared__ bf16 PaccH[4096], PaccL[4096], BaccH[4096], BaccL[4096];
  __shared__ bf16 PcH[4096], PcL[4096];
  __shared__ bf16 BcS[4096];
  const int tid = threadIdx.x, lane = tid & 63, w = tid >> 6;
  const int seg = blockIdx.x;
  const size_t chain = blockIdx.y;
  f32x4 Pr[4], Br[4];
  #pragma unroll
  for (int it = 0; it < 4; ++it){
    #pragma unroll
    for (int r = 0; r < 4; ++r){
      int row = 16*w + (lane>>4)*4 + r, col = 16*it + (lane&15);
      Pr[it][r] = (row == col) ? 1.f : 0.f;   // Pacc = I
      Br[it][r] = 0.f;                        // Bacc = 0
    }
  }
  for (int i = 0; i < 8; ++i){
    const size_t cb = (chain*64 + (size_t)seg*8 + i)*4096;
    #pragma unroll
    for (int it = 0; it < 4; ++it)
      #pragma unroll
      for (int r = 0; r < 4; ++r){
        int row = 16*w + (lane>>4)*4 + r, col = 16*it + (lane&15);
        bf2 sp = split2(Pr[it][r]); PaccH[row*64+col] = sp.h; PaccL[row*64+col] = sp.l;
        bf2 sb = split2(Br[it][r]); BaccH[row*64+col] = sb.h; BaccL[row*64+col] = sb.l;
      }
    __syncthreads();   // prev iter's MFMA done -> safe to overwrite PcH/L
    for (int j = tid; j < 1024; j += 256){
      uint4 p = ((const uint4*)(Pg + cb))[j];   // 4 packed elems
      uint2 hh, ll;
      hh.x = (p.x & 0xFFFFu) | (p.y << 16);
      ll.x = (p.x >> 16)     | (p.y & 0xFFFF0000u);
      hh.y = (p.z & 0xFFFFu) | (p.w << 16);
      ll.y = (p.z >> 16)     | (p.w & 0xFFFF0000u);
      ((uint2*)PcH)[j] = hh;
      ((uint2*)PcL)[j] = ll;
    }
    for (int j = tid; j < 512; j += 256)
      ((uint4*)BcS)[j] = ((const uint4*)(Bg + cb))[j];
    __syncthreads();
    f32x4 nP[4], nB[4];
    #pragma unroll
    for (int it = 0; it < 4; ++it){ nP[it] = f32x4_zero(); nB[it] = f32x4_zero(); }
    #pragma unroll
    for (int kk = 0; kk < 2; ++kk){
      bf16x8 aPH = frag64(PaccH, 16*w, kk, lane), aPL = frag64(PaccL, 16*w, kk, lane);
      bf16x8 aBH = frag64(BaccH, 16*w, kk, lane), aBL = frag64(BaccL, 16*w, kk, lane);
      #pragma unroll
      for (int it = 0; it < 4; ++it){
        bf16x8 bH = frag64(PcH, 16*it, kk, lane), bL = frag64(PcL, 16*it, kk, lane);
        nP[it] = mfma16x16x32(aPH, bH, nP[it]);
        nP[it] = mfma16x16x32(aPH, bL, nP[it]);
        nP[it] = mfma16x16x32(aPL, bH, nP[it]);
        nB[it] = mfma16x16x32(aBH, bH, nB[it]);
        nB[it] = mfma16x16x32(aBH, bL, nB[it]);
        nB[it] = mfma16x16x32(aBL, bH, nB[it]);
      }
    }
    #pragma unroll
    for (int it = 0; it < 4; ++it)
      #pragma unroll
      for (int r = 0; r < 4; ++r){
        int row = 16*w + (lane>>4)*4 + r, col = 16*it + (lane&15);
        Pr[it][r] = nP[it][r];
        Br[it][r] = nB[it][r] + (float)BcS[row*64 + col];
      }
  }
  const size_t sb = (chain*8 + seg)*4096;
  #pragma unroll
  for (int it = 0; it < 4; ++it)
    #pragma unroll
    for (int r = 0; r < 4; ++r){
      int row = 16*w + (lane>>4)*4 + r, col = 16*it + (lane&15);
      PsegT[sb + (size_t)col*64 + row] = Pr[it][r];   // transposed (B-operand layout)
      BsegF[sb + (size_t)row*64 + col] = Br[it][r];   // natural
    }
}

// ---------------------------------------------------------------- K4b: segment-level scan (32 blocks, 8 steps)
__global__ __launch_bounds__(256) void k_phaseB2(const float* __restrict__ PsegT, const float* __restrict__ BsegF,
                                                 float* __restrict__ S0g){
  __shared__ bf16 Sh[4096], Sl[4096], Ph[4096], Pl[4096];
  __shared__ float Bf[4096];
  const int tid = threadIdx.x, lane = tid & 63, w = tid >> 6;
  const size_t bid = blockIdx.x;
  f32x4 Sr[4];
  #pragma unroll
  for (int it = 0; it < 4; ++it) Sr[it] = f32x4_zero();
  for (int seg = 0; seg < 8; ++seg){
    const size_t sb  = (bid*8 + seg)*4096;
    const size_t s0b = (bid*64 + (size_t)seg*8)*4096;
    #pragma unroll
    for (int it = 0; it < 4; ++it)
      #pragma unroll
      for (int r = 0; r < 4; ++r){
        int row = 16*w + (lane>>4)*4 + r, col = 16*it + (lane&15);
        S0g[s0b + (size_t)row*64 + col] = Sr[it][r];
        bf2 sp = split2(Sr[it][r]); Sh[row*64+col] = sp.h; Sl[row*64+col] = sp.l;
      }
    __syncthreads();
    for (int j = tid; j < 1024; j += 256){
      float4 pv = ((const float4*)(PsegT + sb))[j];
      bf16x4 ph, pl;
      bf2 u0 = split2(pv.x); ph[0]=u0.h; pl[0]=u0.l;
      bf2 u1 = split2(pv.y); ph[1]=u1.h; pl[1]=u1.l;
      bf2 u2 = split2(pv.z); ph[2]=u2.h; pl[2]=u2.l;
      bf2 u3 = split2(pv.w); ph[3]=u3.h; pl[3]=u3.l;
      ((bf16x4*)Ph)[j] = ph; ((bf16x4*)Pl)[j] = pl;
      ((float4*)Bf)[j] = ((const float4*)(BsegF + sb))[j];
    }
    __syncthreads();
    f32x4 nS[4];
    #pragma unroll
    for (int it = 0; it < 4; ++it) nS[it] = f32x4_zero();
    #pragma unroll
    for (int kk = 0; kk < 2; ++kk){
      bf16x8 aH = frag64(Sh, 16*w, kk, lane), aL = frag64(Sl, 16*w, kk, lane);
      #pragma unroll
      for (int it = 0; it < 4; ++it){
        bf16x8 bH = frag64(Ph, 16*it, kk, lane), bL = frag64(Pl, 16*it, kk, lane);
        nS[it] = mfma16x16x32(aH, bH, nS[it]);
        nS[it] = mfma16x16x32(aH, bL, nS[it]);
        nS[it] = mfma16x16x32(aL, bH, nS[it]);
      }
    }
    #pragma unroll
    for (int it = 0; it < 4; ++it)
      #pragma unroll
      for (int r = 0; r < 4; ++r){
        int row = 16*w + (lane>>4)*4 + r, col = 16*it + (lane&15);
        Sr[it][r] = nS[it][r] + Bf[row*64 + col];
      }
  }
}

// ---------------------------------------------------------------- K4c: within-segment replay (256 blocks, 7 steps)
__global__ __launch_bounds__(256) void k_phaseB3(const uint32_t* __restrict__ Pg,
                                                 const bf16* __restrict__ Bg,
                                                 float* __restrict__ S0g){
  __shared__ bf16 Sh[4096], Sl[4096], Ph[4096], Pl[4096];
  __shared__ bf16 BcS[4096];
  const int tid = threadIdx.x, lane = tid & 63, w = tid >> 6;
  const int seg = blockIdx.x;
  const size_t chain = blockIdx.y;
  const size_t segbase = chain*64 + (size_t)seg*8;
  f32x4 Sr[4];
  #pragma unroll
  for (int it = 0; it < 4; ++it)
    #pragma unroll
    for (int r = 0; r < 4; ++r){
      int row = 16*w + (lane>>4)*4 + r, col = 16*it + (lane&15);
      Sr[it][r] = S0g[segbase*4096 + (size_t)row*64 + col];
    }
  for (int i = 0; i < 7; ++i){
    const size_t cb = (segbase + i)*4096;
    #pragma unroll
    for (int it = 0; it < 4; ++it)
      #pragma unroll
      for (int r = 0; r < 4; ++r){
        int row = 16*w + (lane>>4)*4 + r, col = 16*it + (lane&15);
        bf2 sp = split2(Sr[it][r]); Sh[row*64+col] = sp.h; Sl[row*64+col] = sp.l;
      }
    __syncthreads();
    for (int j = tid; j < 1024; j += 256){
      uint4 p = ((const uint4*)(Pg + cb))[j];
      uint2 hh, ll;
      hh.x = (p.x & 0xFFFFu) | (p.y << 16);
      ll.x = (p.x >> 16)     | (p.y & 0xFFFF0000u);
      hh.y = (p.z & 0xFFFFu) | (p.w << 16);
      ll.y = (p.z >> 16)     | (p.w & 0xFFFF0000u);
      ((uint2*)Ph)[j] = hh;
      ((uint2*)Pl)[j] = ll;
    }
    for (int j = tid; j < 512; j += 256)
      ((uint4*)BcS)[j] = ((const uint4*)(Bg + cb))[j];
    __syncthreads();
    f32x4 nS[4];
    #pragma unroll
    for (int it = 0; it < 4; ++it) nS[it] = f32x4_zero();
    #pragma unroll
    for (int kk = 0; kk < 2; ++kk){
      bf16x8 aH = frag64(Sh, 16*w, kk, lane), aL = frag64(Sl, 16*w, kk, lane);
      #pragma unroll
      for (int it = 0; it < 4; ++it){
        bf16x8 bH = frag64(Ph, 16*it, kk, lane), bL = frag64(Pl, 16*it, kk, lane);
        nS[it] = mfma16x16x32(aH, bH, nS[it]);
        nS[it] = mfma16x16x32(aH, bL, nS[it]);
        nS[it] = mfma16x16x32(aL, bH, nS[it]);
      }
    }
    const size_t outb = (segbase + i + 1)*4096;
    #pragma unroll
    for (int it = 0; it < 4; ++it)
      #pragma unroll
      for (int r = 0; r < 4; ++r){
        int row = 16*w + (lane>>4)*4 + r, col = 16*it + (lane&15);
        float v = nS[it][r] + (float)BcS[row*64 + col];
        Sr[it][r] = v;
        S0g[outb + (size_t)row*64 + col] = v;
      }
  }
}

// ---------------------------------------------------------------- K5: phase C, outputs + fused RMSNorm/gate (2048 blocks)
__global__ __launch_bounds__(256, 2) void k_phaseC(
    const bf16* __restrict__ qhp, const bf16* __restrict__ qlp,
    const bf16* __restrict__ khp, const bf16* __restrict__ klp,
    const bf16* __restrict__ gf, const float* __restrict__ logA,
    const float* __restrict__ S0g, const bf16* __restrict__ Wg, const bf16* __restrict__ Dg,
    const float* __restrict__ rms_w, bf16* __restrict__ yh, bf16* __restrict__ yl){
  __shared__ bf16 Qh[4096], Ql[4096], Kh[4096], Klo[4096];
  __shared__ bf16 Wl_[4096], Dl_[4096];
  __shared__ bf16 S0h[4096], S0l[4096];
  __shared__ bf16 AAg[4096];
  __shared__ bf16 BDt[4096];
  const int tid = threadIdx.x, lane = tid & 63, w = tid >> 6;
  const int c = blockIdx.x, h = blockIdx.y, b = blockIdx.z;
  const size_t tokbase = (size_t)b*4096 + (size_t)c*64;
  const size_t cbase = ((size_t)((b*16 + h)*64 + c)) * 4096;

  { // async stage Q/K (hi/lo) + Wg/Dg with pre-swizzled source
    const int chunk = tid & 7, r0 = tid >> 3;   // r0 0..31; wave w rows 8w..8w+7 per round
    #pragma unroll
    for (int rr = 0; rr < 2; ++rr){
      const int row = 32*rr + r0;
      const int dbase = (32*rr + 8*w)*64;
      const size_t g = (tokbase + row)*1024 + (size_t)h*64 + 8*(chunk ^ (row & 7));
      GLD_LDS16(&qhp[g], &Qh[dbase]);
      if (qlp) GLD_LDS16(&qlp[g], &Ql[dbase]);
      GLD_LDS16(&khp[g], &Kh[dbase]);
      if (klp) GLD_LDS16(&klp[g], &Klo[dbase]);
      const size_t gg = cbase + (size_t)row*64 + 8*(chunk ^ (row & 7));
      GLD_LDS16(&Wg[gg], &Wl_[dbase]);
      GLD_LDS16(&Dg[gg], &Dl_[dbase]);
    }
    if (!qlp){
      uint4 z4; z4.x=0; z4.y=0; z4.z=0; z4.w=0;
      for (int z = tid; z < 512; z += 256){ ((uint4*)Ql)[z] = z4; ((uint4*)Klo)[z] = z4; }
    }
  }
  for (int i = tid; i < 1024; i += 256){
    float4 v = ((const float4*)(S0g + cbase))[i];
    bf16x4 sh, sl;
    bf2 t0 = split2(v.x); sh[0]=t0.h; sl[0]=t0.l;
    bf2 t1 = split2(v.y); sh[1]=t1.h; sl[1]=t1.l;
    bf2 t2 = split2(v.z); sh[2]=t2.h; sl[2]=t2.l;
    bf2 t3 = split2(v.w); sh[3]=t3.h; sl[3]=t3.l;
    int t = i >> 4, off = ((i&15)*4) ^ ((t&7)<<3);
    *(bf16x4*)&S0h[t*64 + off] = sh;
    *(bf16x4*)&S0l[t*64 + off] = sl;
  }
  // per-wave redundant lg cumsum
  float la = logA[(tokbase + lane)*16 + h];
  #pragma unroll
  for (int dlt = 1; dlt < 64; dlt <<= 1){
    float o = __shfl_up(la, dlt);
    if (lane >= dlt) la += o;
  }
  __syncthreads();

  { // AAg = mask_incl(Gamma .* QK^T), 3-product
    const int t0 = 16*w;
    #pragma unroll
    for (int tu = 0; tu < 4; ++tu){
      f32x4 accm = f32x4_zero();
      #pragma unroll
      for (int kk = 0; kk < 2; ++kk){
        bf16x8 aH = fragSwz(Qh,  t0,    kk, lane);
        bf16x8 aL = fragSwz(Ql,  t0,    kk, lane);
        bf16x8 bH = fragSwz(Kh,  16*tu, kk, lane);
        bf16x8 bL = fragSwz(Klo, 16*tu, kk, lane);
        accm = mfma16x16x32(aH, bH, accm);
        accm = mfma16x16x32(aH, bL, accm);
        accm = mfma16x16x32(aL, bH, accm);
      }
      #pragma unroll
      for (int r = 0; r < 4; ++r){
        int row = t0 + (lane>>4)*4 + r, col = 16*tu + (lane&15);
        float lgr = __shfl(la, row), lgc = __shfl(la, col);
        float v = (col <= row) ? accm[r]*__expf(lgr - lgc) : 0.f;
        AAg[row*64 + (col ^ ((row&7)<<3))] = (bf16)v;
      }
    }
  }
  { // BDt[i][tau] = Dloc[tau][i] - (S0 W_hat^T)[i][tau]
    const int i0 = 16*w;
    #pragma unroll
    for (int tu = 0; tu < 4; ++tu){
      f32x4 accm = f32x4_zero();
      #pragma unroll
      for (int kk = 0; kk < 2; ++kk){
        bf16x8 aH = fragSwz(S0h, i0,    kk, lane);
        bf16x8 aL = fragSwz(S0l, i0,    kk, lane);
        bf16x8 bb = fragSwz(Wl_, 16*tu, kk, lane);
        accm = mfma16x16x32(aH, bb, accm);
        accm = mfma16x16x32(aL, bb, accm);
      }
      #pragma unroll
      for (int r = 0; r < 4; ++r){
        int row = i0 + (lane>>4)*4 + r, col = 16*tu + (lane&15);
        float v = (float)Dl_[col*64 + (row ^ ((col&7)<<3))] - accm[r];
        BDt[row*64 + (col ^ ((row&7)<<3))] = (bf16)v;
      }
    }
  }
  __syncthreads();
  for (int i = tid; i < 4096; i += 256){
    int t = i >> 6;                              // uniform per wave per iteration
    float gq = __expf(__shfl(la, t));
    float v = gq * ((float)Qh[i] + (float)Ql[i]);  // swizzle is within-row: row scale layout-agnostic
    bf2 sp = split2(v);
    Qh[i] = sp.h; Ql[i] = sp.l;
  }
  __syncthreads();
  {
    const int t0 = 16*w;
    f32x4 o_acc[4];
    #pragma unroll
    for (int it = 0; it < 4; ++it) o_acc[it] = f32x4_zero();
    #pragma unroll
    for (int kk = 0; kk < 2; ++kk){
      bf16x8 aQh = fragSwz(Qh, t0, kk, lane);
      bf16x8 aQl = fragSwz(Ql, t0, kk, lane);
      bf16x8 aA  = fragSwz(AAg, t0, kk, lane);
      #pragma unroll
      for (int it = 0; it < 4; ++it){
        bf16x8 bSh = fragSwz(S0h, 16*it, kk, lane);
        bf16x8 bSl = fragSwz(S0l, 16*it, kk, lane);
        bf16x8 bD  = fragSwz(BDt, 16*it, kk, lane);
        f32x4 t = o_acc[it];
        t = mfma16x16x32(aQh, bSh, t);
        t = mfma16x16x32(aQh, bSl, t);
        t = mfma16x16x32(aQl, bSh, t);
        t = mfma16x16x32(aA,  bD,  t);
        o_acc[it] = t;
      }
    }
    float rw[4];
    #pragma unroll
    for (int it = 0; it < 4; ++it) rw[it] = rms_w[16*it + (lane&15)];
    #pragma unroll
    for (int r = 0; r < 4; ++r){
      float ss = 0.f;
      #pragma unroll
      for (int it = 0; it < 4; ++it) ss += o_acc[it][r]*o_acc[it][r];
      ss += __shfl_xor(ss, 1); ss += __shfl_xor(ss, 2);
      ss += __shfl_xor(ss, 4); ss += __shfl_xor(ss, 8);
      const float scale = rsqrtf(ss*(1.f/64.f) + 1e-6f);
      const int row = t0 + (lane>>4)*4 + r;
      const size_t tok = tokbase + row;
      #pragma unroll
      for (int it = 0; it < 4; ++it){
        const int col = 16*it + (lane&15);
        float g = (float)gf[tok*1024 + h*64 + col];
        float sg = g / (1.f + __expf(-g));
        float v = o_acc[it][r]*scale*rw[it]*sg;
        bf2 sp = split2(v);
        yh[tok*1024 + h*64 + col] = sp.h;
        yl[tok*1024 + h*64 + col] = sp.l;
      }
    }
  }
}

// ---------------------------------------------------------------- launcher
extern "C" void kernel_launch(void* const* d_in, const int* in_sizes, int n_in,
                              void* d_out, int out_size, void* d_ws, size_t ws_size,
                              hipStream_t stream){
  const float* x     = (const float*)d_in[0];
  const float* Wq    = (const float*)d_in[1];
  const float* Wk    = (const float*)d_in[2];
  const float* Wv    = (const float*)d_in[3];
  const float* Wa    = (const float*)d_in[4];
  const float* Wb    = (const float*)d_in[5];
  const float* A_log = (const float*)d_in[6];
  const float* dt_b  = (const float*)d_in[7];
  const float* Wgt   = (const float*)d_in[8];
  const float* Wo    = (const float*)d_in[9];
  const float* rms_w = (const float*)d_in[10];

  const bool BIG = ws_size >= (size_t)215000000;

  char* ws = (char*)d_ws;
  size_t off = 0;
  auto alloc = [&](size_t bytes)->char*{
    char* p = ws + off;
    off += (bytes + 255) & ~(size_t)255;
    return p;
  };
  const size_t PLANE = (size_t)8192*1024*2;   // bf16 activation plane (16 MiB)
  const size_t WPL   = (size_t)1024*1024*2;   // bf16 weight plane (2 MiB)
  bf16* xh  = (bf16*)alloc(PLANE);            // region also hosts packed Pg (A->B3), then yh
  bf16* xl  = (bf16*)alloc(PLANE);            // (xh+xl contiguous: PLANE is 256-aligned)
  bf16* wqh = (bf16*)alloc(WPL); bf16* wql = (bf16*)alloc(WPL);   // wqh..wgl also hosts Bg
  bf16* wkh = (bf16*)alloc(WPL); bf16* wkl = (bf16*)alloc(WPL);
  bf16* wvh = (bf16*)alloc(WPL); bf16* wvl = (bf16*)alloc(WPL);
  bf16* wgh = (bf16*)alloc(WPL); bf16* wgl = (bf16*)alloc(WPL);
  bf16* woh = (bf16*)alloc(WPL); bf16* wol = (bf16*)alloc(WPL);
  bf16* WabTh = (bf16*)alloc((size_t)32*1024*2);
  bf16* WabTl = (bf16*)alloc((size_t)32*1024*2);
  // q/k as hi/lo bf16 split planes (hi-only in SMALL)
  bf16* qh = nullptr; bf16* ql = nullptr;
  bf16* kh = nullptr; bf16* kl = nullptr;
  if (BIG){
    qh = (bf16*)alloc(PLANE); ql = (bf16*)alloc(PLANE);
    kh = (bf16*)alloc(PLANE); kl = (bf16*)alloc(PLANE);
  } else {
    qh = (bf16*)alloc(PLANE);
    kh = (bf16*)alloc(PLANE);
  }
  float* vf  = (float*)alloc((size_t)8192*1024*4);  // dead after phase A -> hosts S0g
  bf16* gfb  = (bf16*)alloc(PLANE);
  float* logA  = (float*)alloc((size_t)8192*16*4);
  float* betap = (float*)alloc((size_t)8192*16*4);
  bf16* Wg  = (bf16*)alloc((size_t)2048*4096*2);
  bf16* Dg  = (bf16*)alloc((size_t)2048*4096*2);
  uint32_t* Pg = (uint32_t*)xh;       // packed hi|lo P plane, 33.5 MB spanning xh+xl
  float* S0g = vf;                    // 33.5 MiB fp32 (vf dead after phase A)
  bf16* Bg   = wqh;                   // 16 MiB bf16 (projection weights dead)
  float* PsegT = (float*)d_out;       // 4 MiB scratch in d_out (overwritten by final GEMM)
  float* BsegF = (float*)d_out + 1048576;  // next 4 MiB
  bf16* yh = xh;                      // phase C outputs (Pg dead after B3)
  bf16* yl = xl;

  k_cvt_x<<<8192, 256, 0, stream>>>(x, xh, xl, 2097152);
  k_transpose_w5<<<dim3(32,32,5), 256, 0, stream>>>(Wq, Wk, Wv, Wgt, Wo, wqh);
  k_transpose_ab<<<128, 256, 0, stream>>>(Wa, Wb, WabTh, WabTl);

  k_gemm_qkvg<<<dim3(64,32), 256, 0, stream>>>(xh, wqh, qh, ql, kh, kl, vf, gfb);

  k_ab_gemm<<<256, 256, 0, stream>>>(xh, xl, WabTh, WabTl, A_log, dt_b, logA, betap);

  k_phaseA<<<dim3(64,16,2), 128, 0, stream>>>(kh, kl, vf, logA, betap, Wg, Dg, Pg, Bg);
  k_phaseB1<<<dim3(8,32), 256, 0, stream>>>(Pg, Bg, PsegT, BsegF);
  k_phaseB2<<<32, 256, 0, stream>>>(PsegT, BsegF, S0g);
  k_phaseB3<<<dim3(8,32), 256, 0, stream>>>(Pg, Bg, S0g);
  k_phaseC<<<dim3(64,16,2), 256, 0, stream>>>(qh, ql, kh, kl, gfb, logA, S0g, Wg, Dg, rms_w, yh, yl);

  k_gemm3<<<dim3(64,8), 256, 0, stream>>>(yh, yl, woh, wol, nullptr, (float*)d_out);
}

// Round 10
// 496.917 us; speedup vs baseline: 1.0321x; 1.0018x over previous
//
#include <hip/hip_runtime.h>
#include <cstdint>
#include <cstddef>

typedef __bf16 bf16;
typedef __bf16 bf16x4 __attribute__((ext_vector_type(4)));
typedef __bf16 bf16x8 __attribute__((ext_vector_type(8)));
typedef float  f32x4  __attribute__((ext_vector_type(4)));

#define GLD_LDS16(gp, lp) \
  __builtin_amdgcn_global_load_lds((__attribute__((address_space(1))) void*)(gp), \
                                   (__attribute__((address_space(3))) void*)(lp), 16, 0, 0)

__device__ __forceinline__ f32x4 f32x4_zero(){ f32x4 v; v[0]=0.f; v[1]=0.f; v[2]=0.f; v[3]=0.f; return v; }

__device__ __forceinline__ f32x4 mfma16x16x32(bf16x8 a, bf16x8 b, f32x4 c){
  return __builtin_amdgcn_mfma_f32_16x16x32_bf16(a, b, c, 0, 0, 0);
}
// fragment of a 64-col bf16 LDS array (stride 64), LINEAR layout (phaseB kernels)
__device__ __forceinline__ bf16x8 frag64(const bf16* base, int row0, int kk, int lane){
  return *(const bf16x8*)&base[(row0 + (lane&15))*64 + kk*32 + (lane>>4)*8];
}
// fragment of a 64-col bf16 LDS array with XOR bank-swizzle: elem ^= (row&7)<<3
__device__ __forceinline__ bf16x8 fragSwz(const bf16* base, int row0, int kk, int lane){
  const int row = row0 + (lane&15);
  const int off = (kk*32 + (lane>>4)*8) ^ ((row&7)<<3);
  return *(const bf16x8*)&base[row*64 + off];
}
// fragment of a [*][32] bf16 LDS tile (row = 64B = 16 banks) with chunk-XOR swizzle:
// chunk' = chunk ^ ((row>>1)&3). Fixes the 8-way conflict of the linear layout
// (lanes 0-15 read 16 consecutive rows at one chunk -> 2 banks); swizzled: 8 banks, 2-way (free).
__device__ __forceinline__ bf16x8 frag32swz(const bf16* base, int row, int c0){
  return *(const bf16x8*)&base[row*32 + ((c0 ^ ((row>>1)&3))*8)];
}
struct bf2 { bf16 h, l; };
__device__ __forceinline__ bf2 split2(float v){
  bf2 r; r.h = (bf16)v; r.l = (bf16)(v - (float)r.h); return r;
}
// pack hi/lo split of v into one dword: bits(h) | bits(l)<<16
__device__ __forceinline__ uint32_t pack2(float v){
  bf2 s = split2(v);
  union { bf16 b; uint16_t u; } uh, ul;
  uh.b = s.h; ul.b = s.l;
  return (uint32_t)uh.u | ((uint32_t)ul.u << 16);
}

// ---------------------------------------------------------------- K0a: x -> hi/lo bf16 planes
__global__ __launch_bounds__(256) void k_cvt_x(const float* __restrict__ x,
                                               bf16* __restrict__ xh, bf16* __restrict__ xl, int n4){
  int i = blockIdx.x*256 + threadIdx.x;
  if (i < n4){
    float4 v = ((const float4*)x)[i];
    bf16x4 h, l;
    bf2 t0 = split2(v.x); h[0]=t0.h; l[0]=t0.l;
    bf2 t1 = split2(v.y); h[1]=t1.h; l[1]=t1.l;
    bf2 t2 = split2(v.z); h[2]=t2.h; l[2]=t2.l;
    bf2 t3 = split2(v.w); h[3]=t3.h; l[3]=t3.l;
    ((bf16x4*)xh)[i] = h;
    ((bf16x4*)xl)[i] = l;
  }
}

// ---------------------------------------------------------------- K0b: 5x W[k][n] -> Wt hi/lo [n][k], one launch
__global__ __launch_bounds__(256) void k_transpose_w5(const float* __restrict__ W0, const float* __restrict__ W1,
                                                      const float* __restrict__ W2, const float* __restrict__ W3,
                                                      const float* __restrict__ W4, bf16* __restrict__ WtBase){
  __shared__ float tile[32][33];
  const int z = blockIdx.z;
  const float* W = (z==0)?W0:(z==1)?W1:(z==2)?W2:(z==3)?W3:W4;
  bf16* Wth = WtBase + (size_t)z*2097152;
  bf16* Wtl = Wth + 1048576;
  const int k0 = blockIdx.x*32, n0 = blockIdx.y*32;
  const int r = threadIdx.x >> 3, c4 = (threadIdx.x & 7)*4;
  float4 v = *(const float4*)&W[(size_t)(k0+r)*1024 + n0 + c4];
  tile[r][c4+0]=v.x; tile[r][c4+1]=v.y; tile[r][c4+2]=v.z; tile[r][c4+3]=v.w;
  __syncthreads();
  bf16x4 h, l;
  bf2 t0 = split2(tile[c4+0][r]); h[0]=t0.h; l[0]=t0.l;
  bf2 t1 = split2(tile[c4+1][r]); h[1]=t1.h; l[1]=t1.l;
  bf2 t2 = split2(tile[c4+2][r]); h[2]=t2.h; l[2]=t2.l;
  bf2 t3 = split2(tile[c4+3][r]); h[3]=t3.h; l[3]=t3.l;
  *(bf16x4*)&Wth[(size_t)(n0+r)*1024 + k0 + c4] = h;
  *(bf16x4*)&Wtl[(size_t)(n0+r)*1024 + k0 + c4] = l;
}

// ---------------------------------------------------------------- K0c: Walpha/Wbeta [1024][16] -> WabT hi/lo bf16 [32][1024]
__global__ __launch_bounds__(256) void k_transpose_ab(const float* __restrict__ Wa, const float* __restrict__ Wb,
                                                      bf16* __restrict__ WabTh, bf16* __restrict__ WabTl){
  int p = blockIdx.x*256 + threadIdx.x;
  if (p < 32768){
    int o = p >> 10, k = p & 1023;
    float v = (o < 16) ? Wa[k*16 + o] : Wb[k*16 + (o-16)];
    bf2 s = split2(v);
    WabTh[p] = s.h;
    WabTl[p] = s.l;
  }
}

// ---------------------------------------------------------------- K1: split-bf16 MFMA GEMM (3-product), K=1024
// LDS [128][32] tiles with chunk-XOR swizzle (pre-swizzled GLD source + swizzled read)
__global__ __launch_bounds__(256) void k_gemm3(const bf16* __restrict__ Ah, const bf16* __restrict__ Al,
                                               const bf16* __restrict__ Bth, const bf16* __restrict__ Btl,
                                               bf16* __restrict__ Cb, float* __restrict__ Cf){
  __shared__ bf16 Ash[128*32], Asl[128*32];
  __shared__ bf16 Bsh[128*32], Bsl[128*32];
  const int tid = threadIdx.x, lane = tid & 63, w = tid >> 6;
  const int wm = w >> 1, wn = w & 1;
  const size_t m0 = (size_t)blockIdx.x * 128;
  const size_t n0 = (size_t)blockIdx.y * 128;
  f32x4 acc[4][4];
  #pragma unroll
  for (int i=0;i<4;++i)
    #pragma unroll
    for (int j=0;j<4;++j) acc[i][j] = f32x4_zero();

  for (int k0 = 0; k0 < 1024; k0 += 32){
    __syncthreads();
    #pragma unroll
    for (int j = 0; j < 2; ++j){
      const int rbase = 32*w + 16*j;
      const int r = rbase + (lane >> 2);
      const int kk = k0 + (((lane & 3) ^ ((r >> 1) & 3)))*8;   // pre-swizzled source chunk
      GLD_LDS16(&Ah [(m0 + r)*1024 + kk], &Ash[rbase*32]);
      GLD_LDS16(&Al [(m0 + r)*1024 + kk], &Asl[rbase*32]);
      GLD_LDS16(&Bth[(n0 + r)*1024 + kk], &Bsh[rbase*32]);
      GLD_LDS16(&Btl[(n0 + r)*1024 + kk], &Bsl[rbase*32]);
    }
    __syncthreads();
    bf16x8 ah[4], al[4], bh[4], bl[4];
    #pragma unroll
    for (int t=0;t<4;++t){
      const int ra = 64*wm + 16*t + (lane&15);
      const int rb = 64*wn + 16*t + (lane&15);
      const int c0 = lane >> 4;
      ah[t] = frag32swz(Ash, ra, c0);
      al[t] = frag32swz(Asl, ra, c0);
      bh[t] = frag32swz(Bsh, rb, c0);
      bl[t] = frag32swz(Bsl, rb, c0);
    }
    #pragma unroll
    for (int i=0;i<4;++i)
      #pragma unroll
      for (int j=0;j<4;++j){
        f32x4 t = acc[i][j];
        t = mfma16x16x32(ah[i], bh[j], t);
        t = mfma16x16x32(ah[i], bl[j], t);
        t = mfma16x16x32(al[i], bh[j], t);
        acc[i][j] = t;
      }
  }
  #pragma unroll
  for (int i=0;i<4;++i)
    #pragma unroll
    for (int j=0;j<4;++j)
      #pragma unroll
      for (int r=0;r<4;++r){
        size_t row = m0 + 64*wm + 16*i + (lane>>4)*4 + r;
        size_t col = n0 + 64*wn + 16*j + (lane&15);
        float v = acc[i][j][r];
        if (Cf) Cf[row*1024 + col] = v;
        else    Cb[row*1024 + col] = (bf16)v;
      }
}

// ---------------------------------------------------------------- K1b: fused q/k/v/g projection GEMM, K=1024
// grid (64, 32): blockIdx.y>>3 selects matrix {0=q,1=k,2=v,3=g}; (y&7)*128 = n0.
// LDS tiles chunk-XOR swizzled (was 8-way bank conflict: 8.39e6/dispatch in r9).
__global__ __launch_bounds__(256) void k_gemm_qkvg(const bf16* __restrict__ Ah,
    const bf16* __restrict__ WtBase,
    bf16* __restrict__ qh, bf16* __restrict__ ql,
    bf16* __restrict__ kh, bf16* __restrict__ kl,
    float* __restrict__ vf, bf16* __restrict__ gfb){
  __shared__ bf16 Ash[128*32];
  __shared__ bf16 Bsh[128*32];
  const int tid = threadIdx.x, lane = tid & 63, w = tid >> 6;
  const int wm = w >> 1, wn = w & 1;
  const int which = blockIdx.y >> 3;
  const bf16* Bth = WtBase + (size_t)which * 2097152;
  const size_t m0 = (size_t)blockIdx.x * 128;
  const size_t n0 = (size_t)(blockIdx.y & 7) * 128;
  f32x4 acc[4][4];
  #pragma unroll
  for (int i=0;i<4;++i)
    #pragma unroll
    for (int j=0;j<4;++j) acc[i][j] = f32x4_zero();

  for (int k0 = 0; k0 < 1024; k0 += 32){
    __syncthreads();
    #pragma unroll
    for (int j = 0; j < 2; ++j){
      const int rbase = 32*w + 16*j;
      const int r = rbase + (lane >> 2);
      const int kk = k0 + (((lane & 3) ^ ((r >> 1) & 3)))*8;   // pre-swizzled source chunk
      GLD_LDS16(&Ah [(m0 + r)*1024 + kk], &Ash[rbase*32]);
      GLD_LDS16(&Bth[(n0 + r)*1024 + kk], &Bsh[rbase*32]);
    }
    __syncthreads();
    bf16x8 ah[4], bh[4];
    #pragma unroll
    for (int t=0;t<4;++t){
      const int ra = 64*wm + 16*t + (lane&15);
      const int rb = 64*wn + 16*t + (lane&15);
      const int c0 = lane >> 4;
      ah[t] = frag32swz(Ash, ra, c0);
      bh[t] = frag32swz(Bsh, rb, c0);
    }
    #pragma unroll
    for (int i=0;i<4;++i)
      #pragma unroll
      for (int j=0;j<4;++j)
        acc[i][j] = mfma16x16x32(ah[i], bh[j], acc[i][j]);
  }
  #pragma unroll
  for (int i=0;i<4;++i)
    #pragma unroll
    for (int r=0;r<4;++r){
      float sc = 1.f;
      if (which <= 1){   // fused head l2norm (q also /8)
        float ss = 0.f;
        #pragma unroll
        for (int j=0;j<4;++j) ss += acc[i][j][r]*acc[i][j][r];
        ss += __shfl_xor(ss, 1); ss += __shfl_xor(ss, 2);
        ss += __shfl_xor(ss, 4); ss += __shfl_xor(ss, 8);
        sc = ((which==0) ? 0.125f : 1.0f) / fmaxf(sqrtf(ss), 1e-12f);
      }
      #pragma unroll
      for (int j=0;j<4;++j){
        size_t row = m0 + 64*wm + 16*i + (lane>>4)*4 + r;
        size_t col = n0 + 64*wn + 16*j + (lane&15);
        float v = acc[i][j][r]*sc;
        if (which <= 1){
          bf16* Ch = which ? kh : qh;
          bf16* Cl = which ? kl : ql;
          if (Cl){ bf2 sp = split2(v); Ch[row*1024 + col] = sp.h; Cl[row*1024 + col] = sp.l; }
          else   { Ch[row*1024 + col] = (bf16)v; }
        } else if (which == 2){
          vf[row*1024 + col] = v;
        } else {
          gfb[row*1024 + col] = (bf16)v;
        }
      }
    }
}

// ---------------------------------------------------------------- K2: alpha/beta projections as split-bf16 MFMA GEMM
__global__ __launch_bounds__(256) void k_ab_gemm(const bf16* __restrict__ xh, const bf16* __restrict__ xl,
    const bf16* __restrict__ WabTh, const bf16* __restrict__ WabTl,
    const float* __restrict__ A_log, const float* __restrict__ dt_bias,
    float* __restrict__ logA, float* __restrict__ betap){
  __shared__ bf16 Ash[2][2048], Asl[2][2048];   // 32 rows x 64 k per buffer
  const int tid = threadIdx.x, lane = tid & 63, w = tid >> 6;
  const int mt = w >> 1, nt = w & 1;
  const size_t m0 = (size_t)blockIdx.x * 32;
  const int srow = tid >> 3;
  const int scol = 8*((tid & 7) ^ (srow & 7));
  const size_t sg = (m0 + srow)*1024 + scol;

  f32x4 acc = f32x4_zero();
  GLD_LDS16(&xh[sg], &Ash[0][w*512]);
  GLD_LDS16(&xl[sg], &Asl[0][w*512]);
  for (int s = 0; s < 16; ++s){
    const int cur = s & 1;
    __syncthreads();                    // implicit vmcnt(0): buf[cur] staged
    if (s + 1 < 16){
      const size_t g = sg + (size_t)(s+1)*64;
      GLD_LDS16(&xh[g], &Ash[cur^1][w*512]);
      GLD_LDS16(&xl[g], &Asl[cur^1][w*512]);
    }
    const int k0 = s*64;
    #pragma unroll
    for (int kk = 0; kk < 2; ++kk){
      bf16x8 aH = fragSwz(Ash[cur], 16*mt, kk, lane);
      bf16x8 aL = fragSwz(Asl[cur], 16*mt, kk, lane);
      const size_t bo = (size_t)(16*nt + (lane&15))*1024 + k0 + kk*32 + (lane>>4)*8;
      bf16x8 bH = *(const bf16x8*)&WabTh[bo];
      bf16x8 bL = *(const bf16x8*)&WabTl[bo];
      acc = mfma16x16x32(aH, bH, acc);
      acc = mfma16x16x32(aH, bL, acc);
      acc = mfma16x16x32(aL, bH, acc);
    }
  }
  const int col = lane & 15;
  #pragma unroll
  for (int r = 0; r < 4; ++r){
    const size_t row = m0 + 16*mt + (lane>>4)*4 + r;
    float v = acc[r];
    if (nt == 0){
      float z = v + dt_bias[col];
      float dt = (z > 20.f) ? z : log1pf(expf(z));
      logA[row*16 + col] = -expf(A_log[col]) * dt;   // log(alpha_t)
    } else {
      betap[row*16 + col] = 1.f/(1.f + expf(-v));    // beta_t
    }
  }
}

// ---------------------------------------------------------------- K3: phase A (2048 blocks, 128 thr)
__global__ __launch_bounds__(128, 4) void k_phaseA(const bf16* __restrict__ khp, const bf16* __restrict__ klp,
    const float* __restrict__ vf, const float* __restrict__ logA, const float* __restrict__ betap,
    bf16* __restrict__ Wg, bf16* __restrict__ Dg,
    uint32_t* __restrict__ Pg, bf16* __restrict__ Bg){
  __shared__ bf16  Kh[4096], Kl_[4096];   // 8 KiB + 8 KiB
  __shared__ float Ef[4096];              // 16 KiB; row 0 = lg cumsum
  bf16* DT  = Kh;                         // overlay: Dsol^T (after KtT build)
  bf16* WT  = Kl_;                        // overlay: Wsol^T
  bf16* KtT = (bf16*)&Ef[2048];           // overlay: K_til^T (Ef rows 32..63, after solve)
  const int tid = threadIdx.x, lane = tid & 63, wid = tid >> 6;
  const int c = blockIdx.x, h = blockIdx.y, b = blockIdx.z;
  const size_t tokbase = (size_t)b*4096 + (size_t)c*64;
  const size_t cbase = ((size_t)((b*16 + h)*64 + c)) * 4096;

  { // async stage K tile (hi/lo) with pre-swizzled source
    const int chunk = tid & 7, r0 = tid >> 3;       // r0: wave0 0..7, wave1 8..15
    #pragma unroll
    for (int rr = 0; rr < 4; ++rr){
      const int row = 16*rr + r0;
      const size_t g = (tokbase + row)*1024 + (size_t)h*64 + 8*(chunk ^ (row & 7));
      GLD_LDS16(&khp[g], &Kh[(16*rr + 8*wid)*64]);
      if (klp) GLD_LDS16(&klp[g], &Kl_[(16*rr + 8*wid)*64]);
    }
    if (!klp){
      uint4 z4; z4.x=0; z4.y=0; z4.z=0; z4.w=0;
      for (int z = tid; z < 512; z += 128) ((uint4*)Kl_)[z] = z4;
    }
  }
  const float bet = betap[(tokbase + lane)*16 + h];   // per-lane beta_t, t = lane
  if (tid < 64){
    float la = logA[(tokbase + tid)*16 + h];
    #pragma unroll
    for (int dlt = 1; dlt < 64; dlt <<= 1){
      float o = __shfl_up(la, dlt);
      if (lane >= dlt) la += o;
    }
    Ef[tid] = la;                // lg cumsum in E row 0 (row 0 never read by solve)
  }
  __syncthreads();               // GLD staged + lg ready

  // E~[t][tau] = beta_t * (gamma_t/gamma_tau)*(k_t . k_tau), strictly lower; else 0
  #pragma unroll
  for (int tt = 0; tt < 2; ++tt){
    const int t0 = 32*wid + 16*tt;
    #pragma unroll
    for (int tu = 0; tu < 4; ++tu){
      f32x4 accm = f32x4_zero();
      #pragma unroll
      for (int kk = 0; kk < 2; ++kk){
        bf16x8 aH = fragSwz(Kh,  t0,    kk, lane);
        bf16x8 aL = fragSwz(Kl_, t0,    kk, lane);
        bf16x8 bH = fragSwz(Kh,  16*tu, kk, lane);
        bf16x8 bL = fragSwz(Kl_, 16*tu, kk, lane);
        accm = mfma16x16x32(aH, bH, accm);
        accm = mfma16x16x32(aH, bL, accm);
        accm = mfma16x16x32(aL, bH, accm);
      }
      #pragma unroll
      for (int r = 0; r < 4; ++r){
        int row = t0 + (lane>>4)*4 + r, col = 16*tu + (lane&15);
        float bR = __shfl(bet, row);   // beta folded into E row
        float ev = (col < row) ? accm[r]*__expf(Ef[row] - Ef[col])*bR : 0.f;
        if (row > 0) Ef[row*64 + col] = ev;   // row 0 never read; keeps lg intact
      }
    }
  }
  __syncthreads();   // E complete (both waves) before solve reads

  // right-looking blocked forward substitution, beta pre-folded (serial diag -- r5 form)
  float d[64];
  {
    if (wid == 0){
      #pragma unroll
      for (int t = 0; t < 64; ++t)
        d[t] = __shfl(bet, t) * vf[(tokbase + t)*1024 + h*64 + lane];
    } else {
      #pragma unroll
      for (int t = 0; t < 64; ++t){
        int ks = lane ^ ((t&7)<<3);
        d[t] = __shfl(bet, t) * __expf(Ef[t]) * ((float)Kh[t*64 + ks] + (float)Kl_[t*64 + ks]);
      }
    }
    #pragma unroll
    for (int bi = 0; bi < 4; ++bi){
      // diagonal 16x16 unit-lower solve (serial accumulate)
      #pragma unroll
      for (int tt = 0; tt < 16; ++tt){
        const int t = 16*bi + tt;
        float s = 0.f;
        #pragma unroll
        for (int j = 0; j < 16; ++j)
          if (j < tt) s += Ef[t*64 + 16*bi + j] * d[16*bi + j];
        d[t] = d[t] - s;
      }
      // trailing rank-16 update of all later blocks (independent per t)
      #pragma unroll
      for (int b2 = bi + 1; b2 < 4; ++b2)
        #pragma unroll
        for (int tt = 0; tt < 16; ++tt){
          const int t = 16*b2 + tt;
          float a0=0.f,a1=0.f,a2=0.f,a3=0.f;
          #pragma unroll
          for (int q = 0; q < 4; ++q){
            float4 e = *(const float4*)&Ef[t*64 + 16*bi + q*4];
            a0 += e.x * d[16*bi + q*4 + 0];
            a1 += e.y * d[16*bi + q*4 + 1];
            a2 += e.z * d[16*bi + q*4 + 2];
            a3 += e.w * d[16*bi + q*4 + 3];
          }
          d[t] -= (a0+a1)+(a2+a3);
        }
    }
  }
  __syncthreads();   // all Ef/Kh/Kl solve reads done

  // K_til^T[j][t] = (gamma_L/gamma_t) * k[t][j]  (built AFTER solve, into Ef rows 32..63)
  {
    const float gsc = __expf(Ef[63] - Ef[lane]);   // t == lane for the stride-128 loop
    for (int i = tid; i < 4096; i += 128){
      int t = lane, j = i >> 6;
      int ks = j ^ ((t&7)<<3);
      float kv = (float)Kh[t*64 + ks] + (float)Kl_[t*64 + ks];
      KtT[j*64 + (t ^ ((j&7)<<3))] = (bf16)(gsc * kv);
    }
  }
  __syncthreads();   // KtT built; Kh/Kl_ now dead -> DT/WT overlay safe

  const float gL = __expf(Ef[63]);   // Ef row 0 intact (KtT occupies rows 32..63 only)
  {
    bf16* myT = wid ? WT : DT;
    #pragma unroll
    for (int s4 = 0; s4 < 16; ++s4){
      bf16x4 v4;
      v4[0]=(bf16)d[s4*4+0]; v4[1]=(bf16)d[s4*4+1];
      v4[2]=(bf16)d[s4*4+2]; v4[3]=(bf16)d[s4*4+3];
      *(bf16x4*)&myT[lane*64 + ((s4*4) ^ ((lane&7)<<3))] = v4;
    }
    bf16* myG = wid ? Wg : Dg;
    #pragma unroll
    for (int t = 0; t < 64; ++t)
      myG[cbase + (size_t)t*64 + lane] = (bf16)d[t];
  }
  __syncthreads();

  // P^T[j][i] = gamma_L*I - sum_t K_til[t][j]*Wsol[t][i]  (wave0, MFMA, packed hi|lo dword out)
  // B[i][j]   =              sum_t Dsol[t][i]*K_til[t][j]  (wave1, MFMA, bf16 out)
  if (wid == 0){
    #pragma unroll
    for (int tj = 0; tj < 4; ++tj)
      #pragma unroll
      for (int ti = 0; ti < 4; ++ti){
        f32x4 acc = f32x4_zero();
        #pragma unroll
        for (int kk = 0; kk < 2; ++kk)
          acc = mfma16x16x32(fragSwz(KtT, 16*tj, kk, lane), fragSwz(WT, 16*ti, kk, lane), acc);
        #pragma unroll
        for (int r = 0; r < 4; ++r){
          int row = 16*tj + (lane>>4)*4 + r, col = 16*ti + (lane&15);
          float v = ((row == col) ? gL : 0.f) - acc[r];
          Pg[cbase + (size_t)row*64 + col] = pack2(v);
        }
      }
  } else {
    #pragma unroll
    for (int ti = 0; ti < 4; ++ti)
      #pragma unroll
      for (int tj = 0; tj < 4; ++tj){
        f32x4 acc = f32x4_zero();
        #pragma unroll
        for (int kk = 0; kk < 2; ++kk)
          acc = mfma16x16x32(fragSwz(DT, 16*ti, kk, lane), fragSwz(KtT, 16*tj, kk, lane), acc);
        #pragma unroll
        for (int r = 0; r < 4; ++r){
          int row = 16*ti + (lane>>4)*4 + r, col = 16*tj + (lane&15);
          Bg[cbase + (size_t)row*64 + col] = (bf16)acc[r];
        }
      }
  }
}

// ---------------------------------------------------------------- K4a: segment composition (256 blocks: 8 seg x 32 chains)
__global__ __launch_bounds__(256) void k_phaseB1(const uint32_t* __restrict__ Pg,
                                                 const bf16* __restrict__ Bg,
                                                 float* __restrict__ PsegT, float* __restrict__ BsegF){
  __shared__ bf16 PaccH[4096], PaccL[4096], BaccH[4096], BaccL[4096];
  __shared__ bf16 PcH[4096], PcL[4096];
  __shared__ bf16 BcS[4096];
  const int tid = threadIdx.x, lane = tid & 63, w = tid >> 6;
  const int seg = blockIdx.x;
  const size_t chain = blockIdx.y;
  f32x4 Pr[4], Br[4];
  #pragma unroll
  for (int it = 0; it < 4; ++it){
    #pragma unroll
    for (int r = 0; r < 4; ++r){
      int row = 16*w + (lane>>4)*4 + r, col = 16*it + (lane&15);
      Pr[it][r] = (row == col) ? 1.f : 0.f;   // Pacc = I
      Br[it][r] = 0.f;                        // Bacc = 0
    }
  }
  for (int i = 0; i < 8; ++i){
    const size_t cb = (chain*64 + (size_t)seg*8 + i)*4096;
    #pragma unroll
    for (int it = 0; it < 4; ++it)
      #pragma unroll
      for (int r = 0; r < 4; ++r){
        int row = 16*w + (lane>>4)*4 + r, col = 16*it + (lane&15);
        bf2 sp = split2(Pr[it][r]); PaccH[row*64+col] = sp.h; PaccL[row*64+col] = sp.l;
        bf2 sb = split2(Br[it][r]); BaccH[row*64+col] = sb.h; BaccL[row*64+col] = sb.l;
      }
    __syncthreads();   // prev iter's MFMA done -> safe to overwrite PcH/L
    for (int j = tid; j < 1024; j += 256){
      uint4 p = ((const uint4*)(Pg + cb))[j];   // 4 packed elems
      uint2 hh, ll;
      hh.x = (p.x & 0xFFFFu) | (p.y << 16);
      ll.x = (p.x >> 16)     | (p.y & 0xFFFF0000u);
      hh.y = (p.z & 0xFFFFu) | (p.w << 16);
      ll.y = (p.z >> 16)     | (p.w & 0xFFFF0000u);
      ((uint2*)PcH)[j] = hh;
      ((uint2*)PcL)[j] = ll;
    }
    for (int j = tid; j < 512; j += 256)
      ((uint4*)BcS)[j] = ((const uint4*)(Bg + cb))[j];
    __syncthreads();
    f32x4 nP[4], nB[4];
    #pragma unroll
    for (int it = 0; it < 4; ++it){ nP[it] = f32x4_zero(); nB[it] = f32x4_zero(); }
    #pragma unroll
    for (int kk = 0; kk < 2; ++kk){
      bf16x8 aPH = frag64(PaccH, 16*w, kk, lane), aPL = frag64(PaccL, 16*w, kk, lane);
      bf16x8 aBH = frag64(BaccH, 16*w, kk, lane), aBL = frag64(BaccL, 16*w, kk, lane);
      #pragma unroll
      for (int it = 0; it < 4; ++it){
        bf16x8 bH = frag64(PcH, 16*it, kk, lane), bL = frag64(PcL, 16*it, kk, lane);
        nP[it] = mfma16x16x32(aPH, bH, nP[it]);
        nP[it] = mfma16x16x32(aPH, bL, nP[it]);
        nP[it] = mfma16x16x32(aPL, bH, nP[it]);
        nB[it] = mfma16x16x32(aBH, bH, nB[it]);
        nB[it] = mfma16x16x32(aBH, bL, nB[it]);
        nB[it] = mfma16x16x32(aBL, bH, nB[it]);
      }
    }
    #pragma unroll
    for (int it = 0; it < 4; ++it)
      #pragma unroll
      for (int r = 0; r < 4; ++r){
        int row = 16*w + (lane>>4)*4 + r, col = 16*it + (lane&15);
        Pr[it][r] = nP[it][r];
        Br[it][r] = nB[it][r] + (float)BcS[row*64 + col];
      }
  }
  const size_t sb = (chain*8 + seg)*4096;
  #pragma unroll
  for (int it = 0; it < 4; ++it)
    #pragma unroll
    for (int r = 0; r < 4; ++r){
      int row = 16*w + (lane>>4)*4 + r, col = 16*it + (lane&15);
      PsegT[sb + (size_t)col*64 + row] = Pr[it][r];   // transposed (B-operand layout)
      BsegF[sb + (size_t)row*64 + col] = Br[it][r];   // natural
    }
}

// ---------------------------------------------------------------- K4b: segment-level scan (32 blocks, 8 steps)
__global__ __launch_bounds__(256) void k_phaseB2(const float* __restrict__ PsegT, const float* __restrict__ BsegF,
                                                 float* __restrict__ S0g){
  __shared__ bf16 Sh[4096], Sl[4096], Ph[4096], Pl[4096];
  __shared__ float Bf[4096];
  const int tid = threadIdx.x, lane = tid & 63, w = tid >> 6;
  const size_t bid = blockIdx.x;
  f32x4 Sr[4];
  #pragma unroll
  for (int it = 0; it < 4; ++it) Sr[it] = f32x4_zero();
  for (int seg = 0; seg < 8; ++seg){
    const size_t sb  = (bid*8 + seg)*4096;
    const size_t s0b = (bid*64 + (size_t)seg*8)*4096;
    #pragma unroll
    for (int it = 0; it < 4; ++it)
      #pragma unroll
      for (int r = 0; r < 4; ++r){
        int row = 16*w + (lane>>4)*4 + r, col = 16*it + (lane&15);
        S0g[s0b + (size_t)row*64 + col] = Sr[it][r];
        bf2 sp = split2(Sr[it][r]); Sh[row*64+col] = sp.h; Sl[row*64+col] = sp.l;
      }
    __syncthreads();
    for (int j = tid; j < 1024; j += 256){
      float4 pv = ((const float4*)(PsegT + sb))[j];
      bf16x4 ph, pl;
      bf2 u0 = split2(pv.x); ph[0]=u0.h; pl[0]=u0.l;
      bf2 u1 = split2(pv.y); ph[1]=u1.h; pl[1]=u1.l;
      bf2 u2 = split2(pv.z); ph[2]=u2.h; pl[2]=u2.l;
      bf2 u3 = split2(pv.w); ph[3]=u3.h; pl[3]=u3.l;
      ((bf16x4*)Ph)[j] = ph; ((bf16x4*)Pl)[j] = pl;
      ((float4*)Bf)[j] = ((const float4*)(BsegF + sb))[j];
    }
    __syncthreads();
    f32x4 nS[4];
    #pragma unroll
    for (int it = 0; it < 4; ++it) nS[it] = f32x4_zero();
    #pragma unroll
    for (int kk = 0; kk < 2; ++kk){
      bf16x8 aH = frag64(Sh, 16*w, kk, lane), aL = frag64(Sl, 16*w, kk, lane);
      #pragma unroll
      for (int it = 0; it < 4; ++it){
        bf16x8 bH = frag64(Ph, 16*it, kk, lane), bL = frag64(Pl, 16*it, kk, lane);
        nS[it] = mfma16x16x32(aH, bH, nS[it]);
        nS[it] = mfma16x16x32(aH, bL, nS[it]);
        nS[it] = mfma16x16x32(aL, bH, nS[it]);
      }
    }
    #pragma unroll
    for (int it = 0; it < 4; ++it)
      #pragma unroll
      for (int r = 0; r < 4; ++r){
        int row = 16*w + (lane>>4)*4 + r, col = 16*it + (lane&15);
        Sr[it][r] = nS[it][r] + Bf[row*64 + col];
      }
  }
}

// ---------------------------------------------------------------- K4c: within-segment replay (256 blocks, 7 steps)
__global__ __launch_bounds__(256) void k_phaseB3(const uint32_t* __restrict__ Pg,
                                                 const bf16* __restrict__ Bg,
                                                 float* __restrict__ S0g){
  __shared__ bf16 Sh[4096], Sl[4096], Ph[4096], Pl[4096];
  __shared__ bf16 BcS[4096];
  const int tid = threadIdx.x, lane = tid & 63, w = tid >> 6;
  const int seg = blockIdx.x;
  const size_t chain = blockIdx.y;
  const size_t segbase = chain*64 + (size_t)seg*8;
  f32x4 Sr[4];
  #pragma unroll
  for (int it = 0; it < 4; ++it)
    #pragma unroll
    for (int r = 0; r < 4; ++r){
      int row = 16*w + (lane>>4)*4 + r, col = 16*it + (lane&15);
      Sr[it][r] = S0g[segbase*4096 + (size_t)row*64 + col];
    }
  for (int i = 0; i < 7; ++i){
    const size_t cb = (segbase + i)*4096;
    #pragma unroll
    for (int it = 0; it < 4; ++it)
      #pragma unroll
      for (int r = 0; r < 4; ++r){
        int row = 16*w + (lane>>4)*4 + r, col = 16*it + (lane&15);
        bf2 sp = split2(Sr[it][r]); Sh[row*64+col] = sp.h; Sl[row*64+col] = sp.l;
      }
    __syncthreads();
    for (int j = tid; j < 1024; j += 256){
      uint4 p = ((const uint4*)(Pg + cb))[j];
      uint2 hh, ll;
      hh.x = (p.x & 0xFFFFu) | (p.y << 16);
      ll.x = (p.x >> 16)     | (p.y & 0xFFFF0000u);
      hh.y = (p.z & 0xFFFFu) | (p.w << 16);
      ll.y = (p.z >> 16)     | (p.w & 0xFFFF0000u);
      ((uint2*)Ph)[j] = hh;
      ((uint2*)Pl)[j] = ll;
    }
    for (int j = tid; j < 512; j += 256)
      ((uint4*)BcS)[j] = ((const uint4*)(Bg + cb))[j];
    __syncthreads();
    f32x4 nS[4];
    #pragma unroll
    for (int it = 0; it < 4; ++it) nS[it] = f32x4_zero();
    #pragma unroll
    for (int kk = 0; kk < 2; ++kk){
      bf16x8 aH = frag64(Sh, 16*w, kk, lane), aL = frag64(Sl, 16*w, kk, lane);
      #pragma unroll
      for (int it = 0; it < 4; ++it){
        bf16x8 bH = frag64(Ph, 16*it, kk, lane), bL = frag64(Pl, 16*it, kk, lane);
        nS[it] = mfma16x16x32(aH, bH, nS[it]);
        nS[it] = mfma16x16x32(aH, bL, nS[it]);
        nS[it] = mfma16x16x32(aL, bH, nS[it]);
      }
    }
    const size_t outb = (segbase + i + 1)*4096;
    #pragma unroll
    for (int it = 0; it < 4; ++it)
      #pragma unroll
      for (int r = 0; r < 4; ++r){
        int row = 16*w + (lane>>4)*4 + r, col = 16*it + (lane&15);
        float v = nS[it][r] + (float)BcS[row*64 + col];
        Sr[it][r] = v;
        S0g[outb + (size_t)row*64 + col] = v;
      }
  }
}

// ---------------------------------------------------------------- K5: phase C, outputs + fused RMSNorm/gate (2048 blocks)
__global__ __launch_bounds__(256, 2) void k_phaseC(
    const bf16* __restrict__ qhp, const bf16* __restrict__ qlp,
    const bf16* __restrict__ khp, const bf16* __restrict__ klp,
    const bf16* __restrict__ gf, const float* __restrict__ logA,
    const float* __restrict__ S0g, const bf16* __restrict__ Wg, const bf16* __restrict__ Dg,
    const float* __restrict__ rms_w, bf16* __restrict__ yh, bf16* __restrict__ yl){
  __shared__ bf16 Qh[4096], Ql[4096], Kh[4096], Klo[4096];
  __shared__ bf16 Wl_[4096], Dl_[4096];
  __shared__ bf16 S0h[4096], S0l[4096];
  __shared__ bf16 AAg[4096];
  __shared__ bf16 BDt[4096];
  const int tid = threadIdx.x, lane = tid & 63, w = tid >> 6;
  const int c = blockIdx.x, h = blockIdx.y, b = blockIdx.z;
  const size_t tokbase = (size_t)b*4096 + (size_t)c*64;
  const size_t cbase = ((size_t)((b*16 + h)*64 + c)) * 4096;

  { // async stage Q/K (hi/lo) + Wg/Dg with pre-swizzled source
    const int chunk = tid & 7, r0 = tid >> 3;   // r0 0..31; wave w rows 8w..8w+7 per round
    #pragma unroll
    for (int rr = 0; rr < 2; ++rr){
      const int row = 32*rr + r0;
      const int dbase = (32*rr + 8*w)*64;
      const size_t g = (tokbase + row)*1024 + (size_t)h*64 + 8*(chunk ^ (row & 7));
      GLD_LDS16(&qhp[g], &Qh[dbase]);
      if (qlp) GLD_LDS16(&qlp[g], &Ql[dbase]);
      GLD_LDS16(&khp[g], &Kh[dbase]);
      if (klp) GLD_LDS16(&klp[g], &Klo[dbase]);
      const size_t gg = cbase + (size_t)row*64 + 8*(chunk ^ (row & 7));
      GLD_LDS16(&Wg[gg], &Wl_[dbase]);
      GLD_LDS16(&Dg[gg], &Dl_[dbase]);
    }
    if (!qlp){
      uint4 z4; z4.x=0; z4.y=0; z4.z=0; z4.w=0;
      for (int z = tid; z < 512; z += 256){ ((uint4*)Ql)[z] = z4; ((uint4*)Klo)[z] = z4; }
    }
  }
  for (int i = tid; i < 1024; i += 256){
    float4 v = ((const float4*)(S0g + cbase))[i];
    bf16x4 sh, sl;
    bf2 t0 = split2(v.x); sh[0]=t0.h; sl[0]=t0.l;
    bf2 t1 = split2(v.y); sh[1]=t1.h; sl[1]=t1.l;
    bf2 t2 = split2(v.z); sh[2]=t2.h; sl[2]=t2.l;
    bf2 t3 = split2(v.w); sh[3]=t3.h; sl[3]=t3.l;
    int t = i >> 4, off = ((i&15)*4) ^ ((t&7)<<3);
    *(bf16x4*)&S0h[t*64 + off] = sh;
    *(bf16x4*)&S0l[t*64 + off] = sl;
  }
  // per-wave redundant lg cumsum
  float la = logA[(tokbase + lane)*16 + h];
  #pragma unroll
  for (int dlt = 1; dlt < 64; dlt <<= 1){
    float o = __shfl_up(la, dlt);
    if (lane >= dlt) la += o;
  }
  __syncthreads();

  { // AAg = mask_incl(Gamma .* QK^T), 3-product
    const int t0 = 16*w;
    #pragma unroll
    for (int tu = 0; tu < 4; ++tu){
      f32x4 accm = f32x4_zero();
      #pragma unroll
      for (int kk = 0; kk < 2; ++kk){
        bf16x8 aH = fragSwz(Qh,  t0,    kk, lane);
        bf16x8 aL = fragSwz(Ql,  t0,    kk, lane);
        bf16x8 bH = fragSwz(Kh,  16*tu, kk, lane);
        bf16x8 bL = fragSwz(Klo, 16*tu, kk, lane);
        accm = mfma16x16x32(aH, bH, accm);
        accm = mfma16x16x32(aH, bL, accm);
        accm = mfma16x16x32(aL, bH, accm);
      }
      #pragma unroll
      for (int r = 0; r < 4; ++r){
        int row = t0 + (lane>>4)*4 + r, col = 16*tu + (lane&15);
        float lgr = __shfl(la, row), lgc = __shfl(la, col);
        float v = (col <= row) ? accm[r]*__expf(lgr - lgc) : 0.f;
        AAg[row*64 + (col ^ ((row&7)<<3))] = (bf16)v;
      }
    }
  }
  { // BDt[i][tau] = Dloc[tau][i] - (S0 W_hat^T)[i][tau]
    const int i0 = 16*w;
    #pragma unroll
    for (int tu = 0; tu < 4; ++tu){
      f32x4 accm = f32x4_zero();
      #pragma unroll
      for (int kk = 0; kk < 2; ++kk){
        bf16x8 aH = fragSwz(S0h, i0,    kk, lane);
        bf16x8 aL = fragSwz(S0l, i0,    kk, lane);
        bf16x8 bb = fragSwz(Wl_, 16*tu, kk, lane);
        accm = mfma16x16x32(aH, bb, accm);
        accm = mfma16x16x32(aL, bb, accm);
      }
      #pragma unroll
      for (int r = 0; r < 4; ++r){
        int row = i0 + (lane>>4)*4 + r, col = 16*tu + (lane&15);
        float v = (float)Dl_[col*64 + (row ^ ((col&7)<<3))] - accm[r];
        BDt[row*64 + (col ^ ((row&7)<<3))] = (bf16)v;
      }
    }
  }
  __syncthreads();
  for (int i = tid; i < 4096; i += 256){
    int t = i >> 6;                              // uniform per wave per iteration
    float gq = __expf(__shfl(la, t));
    float v = gq * ((float)Qh[i] + (float)Ql[i]);  // swizzle is within-row: row scale layout-agnostic
    bf2 sp = split2(v);
    Qh[i] = sp.h; Ql[i] = sp.l;
  }
  __syncthreads();
  {
    const int t0 = 16*w;
    f32x4 o_acc[4];
    #pragma unroll
    for (int it = 0; it < 4; ++it) o_acc[it] = f32x4_zero();
    #pragma unroll
    for (int kk = 0; kk < 2; ++kk){
      bf16x8 aQh = fragSwz(Qh, t0, kk, lane);
      bf16x8 aQl = fragSwz(Ql, t0, kk, lane);
      bf16x8 aA  = fragSwz(AAg, t0, kk, lane);
      #pragma unroll
      for (int it = 0; it < 4; ++it){
        bf16x8 bSh = fragSwz(S0h, 16*it, kk, lane);
        bf16x8 bSl = fragSwz(S0l, 16*it, kk, lane);
        bf16x8 bD  = fragSwz(BDt, 16*it, kk, lane);
        f32x4 t = o_acc[it];
        t = mfma16x16x32(aQh, bSh, t);
        t = mfma16x16x32(aQh, bSl, t);
        t = mfma16x16x32(aQl, bSh, t);
        t = mfma16x16x32(aA,  bD,  t);
        o_acc[it] = t;
      }
    }
    float rw[4];
    #pragma unroll
    for (int it = 0; it < 4; ++it) rw[it] = rms_w[16*it + (lane&15)];
    #pragma unroll
    for (int r = 0; r < 4; ++r){
      float ss = 0.f;
      #pragma unroll
      for (int it = 0; it < 4; ++it) ss += o_acc[it][r]*o_acc[it][r];
      ss += __shfl_xor(ss, 1); ss += __shfl_xor(ss, 2);
      ss += __shfl_xor(ss, 4); ss += __shfl_xor(ss, 8);
      const float scale = rsqrtf(ss*(1.f/64.f) + 1e-6f);
      const int row = t0 + (lane>>4)*4 + r;
      const size_t tok = tokbase + row;
      #pragma unroll
      for (int it = 0; it < 4; ++it){
        const int col = 16*it + (lane&15);
        float g = (float)gf[tok*1024 + h*64 + col];
        float sg = g / (1.f + __expf(-g));
        float v = o_acc[it][r]*scale*rw[it]*sg;
        bf2 sp = split2(v);
        yh[tok*1024 + h*64 + col] = sp.h;
        yl[tok*1024 + h*64 + col] = sp.l;
      }
    }
  }
}

// ---------------------------------------------------------------- launcher
extern "C" void kernel_launch(void* const* d_in, const int* in_sizes, int n_in,
                              void* d_out, int out_size, void* d_ws, size_t ws_size,
                              hipStream_t stream){
  const float* x     = (const float*)d_in[0];
  const float* Wq    = (const float*)d_in[1];
  const float* Wk    = (const float*)d_in[2];
  const float* Wv    = (const float*)d_in[3];
  const float* Wa    = (const float*)d_in[4];
  const float* Wb    = (const float*)d_in[5];
  const float* A_log = (const float*)d_in[6];
  const float* dt_b  = (const float*)d_in[7];
  const float* Wgt   = (const float*)d_in[8];
  const float* Wo    = (const float*)d_in[9];
  const float* rms_w = (const float*)d_in[10];

  const bool BIG = ws_size >= (size_t)215000000;

  char* ws = (char*)d_ws;
  size_t off = 0;
  auto alloc = [&](size_t bytes)->char*{
    char* p = ws + off;
    off += (bytes + 255) & ~(size_t)255;
    return p;
  };
  const size_t PLANE = (size_t)8192*1024*2;   // bf16 activation plane (16 MiB)
  const size_t WPL   = (size_t)1024*1024*2;   // bf16 weight plane (2 MiB)
  bf16* xh  = (bf16*)alloc(PLANE);            // region also hosts packed Pg (A->B3), then yh
  bf16* xl  = (bf16*)alloc(PLANE);            // (xh+xl contiguous: PLANE is 256-aligned)
  bf16* wqh = (bf16*)alloc(WPL); bf16* wql = (bf16*)alloc(WPL);   // wqh..wgl also hosts Bg
  bf16* wkh = (bf16*)alloc(WPL); bf16* wkl = (bf16*)alloc(WPL);
  bf16* wvh = (bf16*)alloc(WPL); bf16* wvl = (bf16*)alloc(WPL);
  bf16* wgh = (bf16*)alloc(WPL); bf16* wgl = (bf16*)alloc(WPL);
  bf16* woh = (bf16*)alloc(WPL); bf16* wol = (bf16*)alloc(WPL);
  bf16* WabTh = (bf16*)alloc((size_t)32*1024*2);
  bf16* WabTl = (bf16*)alloc((size_t)32*1024*2);
  // q/k as hi/lo bf16 split planes (hi-only in SMALL)
  bf16* qh = nullptr; bf16* ql = nullptr;
  bf16* kh = nullptr; bf16* kl = nullptr;
  if (BIG){
    qh = (bf16*)alloc(PLANE); ql = (bf16*)alloc(PLANE);
    kh = (bf16*)alloc(PLANE); kl = (bf16*)alloc(PLANE);
  } else {
    qh = (bf16*)alloc(PLANE);
    kh = (bf16*)alloc(PLANE);
  }
  float* vf  = (float*)alloc((size_t)8192*1024*4);  // dead after phase A -> hosts S0g
  bf16* gfb  = (bf16*)alloc(PLANE);
  float* logA  = (float*)alloc((size_t)8192*16*4);
  float* betap = (float*)alloc((size_t)8192*16*4);
  bf16* Wg  = (bf16*)alloc((size_t)2048*4096*2);
  bf16* Dg  = (bf16*)alloc((size_t)2048*4096*2);
  uint32_t* Pg = (uint32_t*)xh;       // packed hi|lo P plane, 33.5 MB spanning xh+xl
  float* S0g = vf;                    // 33.5 MiB fp32 (vf dead after phase A)
  bf16* Bg   = wqh;                   // 16 MiB bf16 (projection weights dead)
  float* PsegT = (float*)d_out;       // 4 MiB scratch in d_out (overwritten by final GEMM)
  float* BsegF = (float*)d_out + 1048576;  // next 4 MiB
  bf16* yh = xh;                      // phase C outputs (Pg dead after B3)
  bf16* yl = xl;

  k_cvt_x<<<8192, 256, 0, stream>>>(x, xh, xl, 2097152);
  k_transpose_w5<<<dim3(32,32,5), 256, 0, stream>>>(Wq, Wk, Wv, Wgt, Wo, wqh);
  k_transpose_ab<<<128, 256, 0, stream>>>(Wa, Wb, WabTh, WabTl);

  k_gemm_qkvg<<<dim3(64,32), 256, 0, stream>>>(xh, wqh, qh, ql, kh, kl, vf, gfb);

  k_ab_gemm<<<256, 256, 0, stream>>>(xh, xl, WabTh, WabTl, A_log, dt_b, logA, betap);

  k_phaseA<<<dim3(64,16,2), 128, 0, stream>>>(kh, kl, vf, logA, betap, Wg, Dg, Pg, Bg);
  k_phaseB1<<<dim3(8,32), 256, 0, stream>>>(Pg, Bg, PsegT, BsegF);
  k_phaseB2<<<32, 256, 0, stream>>>(PsegT, BsegF, S0g);
  k_phaseB3<<<dim3(8,32), 256, 0, stream>>>(Pg, Bg, S0g);
  k_phaseC<<<dim3(64,16,2), 256, 0, stream>>>(qh, ql, kh, kl, gfb, logA, S0g, Wg, Dg, rms_w, yh, yl);

  k_gemm3<<<dim3(64,8), 256, 0, stream>>>(yh, yl, woh, wol, nullptr, (float*)d_out);
}

// Round 12
// 489.870 us; speedup vs baseline: 1.0469x; 1.0144x over previous
//
#include <hip/hip_runtime.h>
#include <cstdint>
#include <cstddef>

typedef __bf16 bf16;
typedef __bf16 bf16x4 __attribute__((ext_vector_type(4)));
typedef __bf16 bf16x8 __attribute__((ext_vector_type(8)));
typedef float  f32x4  __attribute__((ext_vector_type(4)));

#define GLD_LDS16(gp, lp) \
  __builtin_amdgcn_global_load_lds((__attribute__((address_space(1))) void*)(gp), \
                                   (__attribute__((address_space(3))) void*)(lp), 16, 0, 0)

__device__ __forceinline__ f32x4 f32x4_zero(){ f32x4 v; v[0]=0.f; v[1]=0.f; v[2]=0.f; v[3]=0.f; return v; }

__device__ __forceinline__ f32x4 mfma16x16x32(bf16x8 a, bf16x8 b, f32x4 c){
  return __builtin_amdgcn_mfma_f32_16x16x32_bf16(a, b, c, 0, 0, 0);
}
// fragment of a 64-col bf16 LDS array (stride 64), LINEAR layout (phaseB kernels)
__device__ __forceinline__ bf16x8 frag64(const bf16* base, int row0, int kk, int lane){
  return *(const bf16x8*)&base[(row0 + (lane&15))*64 + kk*32 + (lane>>4)*8];
}
// fragment of a 64-col bf16 LDS array with XOR bank-swizzle: elem ^= (row&7)<<3
__device__ __forceinline__ bf16x8 fragSwz(const bf16* base, int row0, int kk, int lane){
  const int row = row0 + (lane&15);
  const int off = (kk*32 + (lane>>4)*8) ^ ((row&7)<<3);
  return *(const bf16x8*)&base[row*64 + off];
}
// fragment of a [*][32] bf16 LDS tile (row = 64B = 16 banks) with chunk-XOR swizzle:
// chunk' = chunk ^ ((row>>1)&3). Fixes the 8-way conflict of the linear layout.
__device__ __forceinline__ bf16x8 frag32swz(const bf16* base, int row, int c0){
  return *(const bf16x8*)&base[row*32 + ((c0 ^ ((row>>1)&3))*8)];
}
struct bf2 { bf16 h, l; };
__device__ __forceinline__ bf2 split2(float v){
  bf2 r; r.h = (bf16)v; r.l = (bf16)(v - (float)r.h); return r;
}
// pack hi/lo split of v into one dword: bits(h) | bits(l)<<16
__device__ __forceinline__ uint32_t pack2(float v){
  bf2 s = split2(v);
  union { bf16 b; uint16_t u; } uh, ul;
  uh.b = s.h; ul.b = s.l;
  return (uint32_t)uh.u | ((uint32_t)ul.u << 16);
}

// ---------------------------------------------------------------- K0a: x -> hi/lo bf16 planes
__global__ __launch_bounds__(256) void k_cvt_x(const float* __restrict__ x,
                                               bf16* __restrict__ xh, bf16* __restrict__ xl, int n4){
  int i = blockIdx.x*256 + threadIdx.x;
  if (i < n4){
    float4 v = ((const float4*)x)[i];
    bf16x4 h, l;
    bf2 t0 = split2(v.x); h[0]=t0.h; l[0]=t0.l;
    bf2 t1 = split2(v.y); h[1]=t1.h; l[1]=t1.l;
    bf2 t2 = split2(v.z); h[2]=t2.h; l[2]=t2.l;
    bf2 t3 = split2(v.w); h[3]=t3.h; l[3]=t3.l;
    ((bf16x4*)xh)[i] = h;
    ((bf16x4*)xl)[i] = l;
  }
}

// ---------------------------------------------------------------- K0b: 5x W[k][n] -> Wt hi/lo [n][k], one launch
__global__ __launch_bounds__(256) void k_transpose_w5(const float* __restrict__ W0, const float* __restrict__ W1,
                                                      const float* __restrict__ W2, const float* __restrict__ W3,
                                                      const float* __restrict__ W4, bf16* __restrict__ WtBase){
  __shared__ float tile[32][33];
  const int z = blockIdx.z;
  const float* W = (z==0)?W0:(z==1)?W1:(z==2)?W2:(z==3)?W3:W4;
  bf16* Wth = WtBase + (size_t)z*2097152;
  bf16* Wtl = Wth + 1048576;
  const int k0 = blockIdx.x*32, n0 = blockIdx.y*32;
  const int r = threadIdx.x >> 3, c4 = (threadIdx.x & 7)*4;
  float4 v = *(const float4*)&W[(size_t)(k0+r)*1024 + n0 + c4];
  tile[r][c4+0]=v.x; tile[r][c4+1]=v.y; tile[r][c4+2]=v.z; tile[r][c4+3]=v.w;
  __syncthreads();
  bf16x4 h, l;
  bf2 t0 = split2(tile[c4+0][r]); h[0]=t0.h; l[0]=t0.l;
  bf2 t1 = split2(tile[c4+1][r]); h[1]=t1.h; l[1]=t1.l;
  bf2 t2 = split2(tile[c4+2][r]); h[2]=t2.h; l[2]=t2.l;
  bf2 t3 = split2(tile[c4+3][r]); h[3]=t3.h; l[3]=t3.l;
  *(bf16x4*)&Wth[(size_t)(n0+r)*1024 + k0 + c4] = h;
  *(bf16x4*)&Wtl[(size_t)(n0+r)*1024 + k0 + c4] = l;
}

// ---------------------------------------------------------------- K0c: Walpha/Wbeta [1024][16] -> WabT hi/lo bf16 [32][1024]
__global__ __launch_bounds__(256) void k_transpose_ab(const float* __restrict__ Wa, const float* __restrict__ Wb,
                                                      bf16* __restrict__ WabTh, bf16* __restrict__ WabTl){
  int p = blockIdx.x*256 + threadIdx.x;
  if (p < 32768){
    int o = p >> 10, k = p & 1023;
    float v = (o < 16) ? Wa[k*16 + o] : Wb[k*16 + (o-16)];
    bf2 s = split2(v);
    WabTh[p] = s.h;
    WabTl[p] = s.l;
  }
}

// ---------------------------------------------------------------- K1: split-bf16 MFMA GEMM (3-product), K=1024
// LDS [128][32] tiles with chunk-XOR swizzle (pre-swizzled GLD source + swizzled read)
__global__ __launch_bounds__(256) void k_gemm3(const bf16* __restrict__ Ah, const bf16* __restrict__ Al,
                                               const bf16* __restrict__ Bth, const bf16* __restrict__ Btl,
                                               bf16* __restrict__ Cb, float* __restrict__ Cf){
  __shared__ bf16 Ash[128*32], Asl[128*32];
  __shared__ bf16 Bsh[128*32], Bsl[128*32];
  const int tid = threadIdx.x, lane = tid & 63, w = tid >> 6;
  const int wm = w >> 1, wn = w & 1;
  const size_t m0 = (size_t)blockIdx.x * 128;
  const size_t n0 = (size_t)blockIdx.y * 128;
  f32x4 acc[4][4];
  #pragma unroll
  for (int i=0;i<4;++i)
    #pragma unroll
    for (int j=0;j<4;++j) acc[i][j] = f32x4_zero();

  for (int k0 = 0; k0 < 1024; k0 += 32){
    __syncthreads();
    #pragma unroll
    for (int j = 0; j < 2; ++j){
      const int rbase = 32*w + 16*j;
      const int r = rbase + (lane >> 2);
      const int kk = k0 + (((lane & 3) ^ ((r >> 1) & 3)))*8;   // pre-swizzled source chunk
      GLD_LDS16(&Ah [(m0 + r)*1024 + kk], &Ash[rbase*32]);
      GLD_LDS16(&Al [(m0 + r)*1024 + kk], &Asl[rbase*32]);
      GLD_LDS16(&Bth[(n0 + r)*1024 + kk], &Bsh[rbase*32]);
      GLD_LDS16(&Btl[(n0 + r)*1024 + kk], &Bsl[rbase*32]);
    }
    __syncthreads();
    bf16x8 ah[4], al[4], bh[4], bl[4];
    #pragma unroll
    for (int t=0;t<4;++t){
      const int ra = 64*wm + 16*t + (lane&15);
      const int rb = 64*wn + 16*t + (lane&15);
      const int c0 = lane >> 4;
      ah[t] = frag32swz(Ash, ra, c0);
      al[t] = frag32swz(Asl, ra, c0);
      bh[t] = frag32swz(Bsh, rb, c0);
      bl[t] = frag32swz(Bsl, rb, c0);
    }
    #pragma unroll
    for (int i=0;i<4;++i)
      #pragma unroll
      for (int j=0;j<4;++j){
        f32x4 t = acc[i][j];
        t = mfma16x16x32(ah[i], bh[j], t);
        t = mfma16x16x32(ah[i], bl[j], t);
        t = mfma16x16x32(al[i], bh[j], t);
        acc[i][j] = t;
      }
  }
  #pragma unroll
  for (int i=0;i<4;++i)
    #pragma unroll
    for (int j=0;j<4;++j)
      #pragma unroll
      for (int r=0;r<4;++r){
        size_t row = m0 + 64*wm + 16*i + (lane>>4)*4 + r;
        size_t col = n0 + 64*wn + 16*j + (lane&15);
        float v = acc[i][j][r];
        if (Cf) Cf[row*1024 + col] = v;
        else    Cb[row*1024 + col] = (bf16)v;
      }
}

// ---------------------------------------------------------------- K1b: fused q/k/v/g projection GEMM, K=1024
// grid (64, 32): blockIdx.y>>3 selects matrix {0=q,1=k,2=v,3=g}; (y&7)*128 = n0.
// T3-minimum 2-phase prefetch: double-buffered LDS, STAGE(s+1) issued BEFORE computing
// tile s, ONE barrier per K-step (its implicit vmcnt(0) drain readies buf[cur]).
__global__ __launch_bounds__(256) void k_gemm_qkvg(const bf16* __restrict__ Ah,
    const bf16* __restrict__ WtBase,
    bf16* __restrict__ qh, bf16* __restrict__ ql,
    bf16* __restrict__ kh, bf16* __restrict__ kl,
    float* __restrict__ vf, bf16* __restrict__ gfb){
  __shared__ bf16 Ash[2][4096];
  __shared__ bf16 Bsh[2][4096];
  const int tid = threadIdx.x, lane = tid & 63, w = tid >> 6;
  const int wm = w >> 1, wn = w & 1;
  const int which = blockIdx.y >> 3;
  const bf16* Bth = WtBase + (size_t)which * 2097152;
  const size_t m0 = (size_t)blockIdx.x * 128;
  const size_t n0 = (size_t)(blockIdx.y & 7) * 128;
  f32x4 acc[4][4];
  #pragma unroll
  for (int i=0;i<4;++i)
    #pragma unroll
    for (int j=0;j<4;++j) acc[i][j] = f32x4_zero();

  auto STAGE = [&](int s, int buf){
    #pragma unroll
    for (int j = 0; j < 2; ++j){
      const int rbase = 32*w + 16*j;
      const int r = rbase + (lane >> 2);
      const int kk = s*32 + (((lane & 3) ^ ((r >> 1) & 3)))*8;   // pre-swizzled source chunk
      GLD_LDS16(&Ah [(m0 + r)*1024 + kk], &Ash[buf][rbase*32]);
      GLD_LDS16(&Bth[(n0 + r)*1024 + kk], &Bsh[buf][rbase*32]);
    }
  };

  STAGE(0, 0);
  for (int s = 0; s < 32; ++s){
    const int cur = s & 1;
    __syncthreads();                 // implicit vmcnt(0): buf[cur] staged; prev reads done
    if (s + 1 < 32) STAGE(s + 1, cur ^ 1);   // overlap next-tile loads with this tile's MFMA
    bf16x8 ah[4], bh[4];
    #pragma unroll
    for (int t=0;t<4;++t){
      const int ra = 64*wm + 16*t + (lane&15);
      const int rb = 64*wn + 16*t + (lane&15);
      const int c0 = lane >> 4;
      ah[t] = frag32swz(Ash[cur], ra, c0);
      bh[t] = frag32swz(Bsh[cur], rb, c0);
    }
    #pragma unroll
    for (int i=0;i<4;++i)
      #pragma unroll
      for (int j=0;j<4;++j)
        acc[i][j] = mfma16x16x32(ah[i], bh[j], acc[i][j]);
  }
  #pragma unroll
  for (int i=0;i<4;++i)
    #pragma unroll
    for (int r=0;r<4;++r){
      float sc = 1.f;
      if (which <= 1){   // fused head l2norm (q also /8)
        float ss = 0.f;
        #pragma unroll
        for (int j=0;j<4;++j) ss += acc[i][j][r]*acc[i][j][r];
        ss += __shfl_xor(ss, 1); ss += __shfl_xor(ss, 2);
        ss += __shfl_xor(ss, 4); ss += __shfl_xor(ss, 8);
        sc = ((which==0) ? 0.125f : 1.0f) / fmaxf(sqrtf(ss), 1e-12f);
      }
      #pragma unroll
      for (int j=0;j<4;++j){
        size_t row = m0 + 64*wm + 16*i + (lane>>4)*4 + r;
        size_t col = n0 + 64*wn + 16*j + (lane&15);
        float v = acc[i][j][r]*sc;
        if (which <= 1){
          bf16* Ch = which ? kh : qh;
          bf16* Cl = which ? kl : ql;
          if (Cl){ bf2 sp = split2(v); Ch[row*1024 + col] = sp.h; Cl[row*1024 + col] = sp.l; }
          else   { Ch[row*1024 + col] = (bf16)v; }
        } else if (which == 2){
          vf[row*1024 + col] = v;
        } else {
          gfb[row*1024 + col] = (bf16)v;
        }
      }
    }
}

// ---------------------------------------------------------------- K2: alpha/beta projections as split-bf16 MFMA GEMM
__global__ __launch_bounds__(256) void k_ab_gemm(const bf16* __restrict__ xh, const bf16* __restrict__ xl,
    const bf16* __restrict__ WabTh, const bf16* __restrict__ WabTl,
    const float* __restrict__ A_log, const float* __restrict__ dt_bias,
    float* __restrict__ logA, float* __restrict__ betap){
  __shared__ bf16 Ash[2][2048], Asl[2][2048];   // 32 rows x 64 k per buffer
  const int tid = threadIdx.x, lane = tid & 63, w = tid >> 6;
  const int mt = w >> 1, nt = w & 1;
  const size_t m0 = (size_t)blockIdx.x * 32;
  const int srow = tid >> 3;
  const int scol = 8*((tid & 7) ^ (srow & 7));
  const size_t sg = (m0 + srow)*1024 + scol;

  f32x4 acc = f32x4_zero();
  GLD_LDS16(&xh[sg], &Ash[0][w*512]);
  GLD_LDS16(&xl[sg], &Asl[0][w*512]);
  for (int s = 0; s < 16; ++s){
    const int cur = s & 1;
    __syncthreads();                    // implicit vmcnt(0): buf[cur] staged
    if (s + 1 < 16){
      const size_t g = sg + (size_t)(s+1)*64;
      GLD_LDS16(&xh[g], &Ash[cur^1][w*512]);
      GLD_LDS16(&xl[g], &Asl[cur^1][w*512]);
    }
    const int k0 = s*64;
    #pragma unroll
    for (int kk = 0; kk < 2; ++kk){
      bf16x8 aH = fragSwz(Ash[cur], 16*mt, kk, lane);
      bf16x8 aL = fragSwz(Asl[cur], 16*mt, kk, lane);
      const size_t bo = (size_t)(16*nt + (lane&15))*1024 + k0 + kk*32 + (lane>>4)*8;
      bf16x8 bH = *(const bf16x8*)&WabTh[bo];
      bf16x8 bL = *(const bf16x8*)&WabTl[bo];
      acc = mfma16x16x32(aH, bH, acc);
      acc = mfma16x16x32(aH, bL, acc);
      acc = mfma16x16x32(aL, bH, acc);
    }
  }
  const int col = lane & 15;
  #pragma unroll
  for (int r = 0; r < 4; ++r){
    const size_t row = m0 + 16*mt + (lane>>4)*4 + r;
    float v = acc[r];
    if (nt == 0){
      float z = v + dt_bias[col];
      float dt = (z > 20.f) ? z : log1pf(expf(z));
      logA[row*16 + col] = -expf(A_log[col]) * dt;   // log(alpha_t)
    } else {
      betap[row*16 + col] = 1.f/(1.f + expf(-v));    // beta_t
    }
  }
}

// ---------------------------------------------------------------- K3: phase A (2048 blocks, 128 thr)
__global__ __launch_bounds__(128, 4) void k_phaseA(const bf16* __restrict__ khp, const bf16* __restrict__ klp,
    const float* __restrict__ vf, const float* __restrict__ logA, const float* __restrict__ betap,
    bf16* __restrict__ Wg, bf16* __restrict__ Dg,
    uint32_t* __restrict__ Pg, bf16* __restrict__ Bg){
  __shared__ bf16  Kh[4096], Kl_[4096];   // 8 KiB + 8 KiB
  __shared__ float Ef[4096];              // 16 KiB; row 0 = lg cumsum
  bf16* DT  = Kh;                         // overlay: Dsol^T (after KtT build)
  bf16* WT  = Kl_;                        // overlay: Wsol^T
  bf16* KtT = (bf16*)&Ef[2048];           // overlay: K_til^T (Ef rows 32..63, after solve)
  const int tid = threadIdx.x, lane = tid & 63, wid = tid >> 6;
  const int c = blockIdx.x, h = blockIdx.y, b = blockIdx.z;
  const size_t tokbase = (size_t)b*4096 + (size_t)c*64;
  const size_t cbase = ((size_t)((b*16 + h)*64 + c)) * 4096;

  { // async stage K tile (hi/lo) with pre-swizzled source
    const int chunk = tid & 7, r0 = tid >> 3;       // r0: wave0 0..7, wave1 8..15
    #pragma unroll
    for (int rr = 0; rr < 4; ++rr){
      const int row = 16*rr + r0;
      const size_t g = (tokbase + row)*1024 + (size_t)h*64 + 8*(chunk ^ (row & 7));
      GLD_LDS16(&khp[g], &Kh[(16*rr + 8*wid)*64]);
      if (klp) GLD_LDS16(&klp[g], &Kl_[(16*rr + 8*wid)*64]);
    }
    if (!klp){
      uint4 z4; z4.x=0; z4.y=0; z4.z=0; z4.w=0;
      for (int z = tid; z < 512; z += 128) ((uint4*)Kl_)[z] = z4;
    }
  }
  const float bet = betap[(tokbase + lane)*16 + h];   // per-lane beta_t, t = lane
  if (tid < 64){
    float la = logA[(tokbase + tid)*16 + h];
    #pragma unroll
    for (int dlt = 1; dlt < 64; dlt <<= 1){
      float o = __shfl_up(la, dlt);
      if (lane >= dlt) la += o;
    }
    Ef[tid] = la;                // lg cumsum in E row 0 (row 0 never read by solve)
  }
  __syncthreads();               // GLD staged + lg ready

  // E~[t][tau] = beta_t * (gamma_t/gamma_tau)*(k_t . k_tau), strictly lower; else 0
  #pragma unroll
  for (int tt = 0; tt < 2; ++tt){
    const int t0 = 32*wid + 16*tt;
    #pragma unroll
    for (int tu = 0; tu < 4; ++tu){
      f32x4 accm = f32x4_zero();
      #pragma unroll
      for (int kk = 0; kk < 2; ++kk){
        bf16x8 aH = fragSwz(Kh,  t0,    kk, lane);
        bf16x8 aL = fragSwz(Kl_, t0,    kk, lane);
        bf16x8 bH = fragSwz(Kh,  16*tu, kk, lane);
        bf16x8 bL = fragSwz(Kl_, 16*tu, kk, lane);
        accm = mfma16x16x32(aH, bH, accm);
        accm = mfma16x16x32(aH, bL, accm);
        accm = mfma16x16x32(aL, bH, accm);
      }
      #pragma unroll
      for (int r = 0; r < 4; ++r){
        int row = t0 + (lane>>4)*4 + r, col = 16*tu + (lane&15);
        float bR = __shfl(bet, row);   // beta folded into E row
        float ev = (col < row) ? accm[r]*__expf(Ef[row] - Ef[col])*bR : 0.f;
        if (row > 0) Ef[row*64 + col] = ev;   // row 0 never read; keeps lg intact
      }
    }
  }
  __syncthreads();   // E complete (both waves) before solve reads

  // right-looking blocked forward substitution, beta pre-folded (serial diag -- r5 form)
  float d[64];
  {
    if (wid == 0){
      #pragma unroll
      for (int t = 0; t < 64; ++t)
        d[t] = __shfl(bet, t) * vf[(tokbase + t)*1024 + h*64 + lane];
    } else {
      #pragma unroll
      for (int t = 0; t < 64; ++t){
        int ks = lane ^ ((t&7)<<3);
        d[t] = __shfl(bet, t) * __expf(Ef[t]) * ((float)Kh[t*64 + ks] + (float)Kl_[t*64 + ks]);
      }
    }
    #pragma unroll
    for (int bi = 0; bi < 4; ++bi){
      // diagonal 16x16 unit-lower solve (serial accumulate)
      #pragma unroll
      for (int tt = 0; tt < 16; ++tt){
        const int t = 16*bi + tt;
        float s = 0.f;
        #pragma unroll
        for (int j = 0; j < 16; ++j)
          if (j < tt) s += Ef[t*64 + 16*bi + j] * d[16*bi + j];
        d[t] = d[t] - s;
      }
      // trailing rank-16 update of all later blocks (independent per t)
      #pragma unroll
      for (int b2 = bi + 1; b2 < 4; ++b2)
        #pragma unroll
        for (int tt = 0; tt < 16; ++tt){
          const int t = 16*b2 + tt;
          float a0=0.f,a1=0.f,a2=0.f,a3=0.f;
          #pragma unroll
          for (int q = 0; q < 4; ++q){
            float4 e = *(const float4*)&Ef[t*64 + 16*bi + q*4];
            a0 += e.x * d[16*bi + q*4 + 0];
            a1 += e.y * d[16*bi + q*4 + 1];
            a2 += e.z * d[16*bi + q*4 + 2];
            a3 += e.w * d[16*bi + q*4 + 3];
          }
          d[t] -= (a0+a1)+(a2+a3);
        }
    }
  }
  __syncthreads();   // all Ef/Kh/Kl solve reads done

  // K_til^T[j][t] = (gamma_L/gamma_t) * k[t][j]  (built AFTER solve, into Ef rows 32..63)
  {
    const float gsc = __expf(Ef[63] - Ef[lane]);   // t == lane for the stride-128 loop
    for (int i = tid; i < 4096; i += 128){
      int t = lane, j = i >> 6;
      int ks = j ^ ((t&7)<<3);
      float kv = (float)Kh[t*64 + ks] + (float)Kl_[t*64 + ks];
      KtT[j*64 + (t ^ ((j&7)<<3))] = (bf16)(gsc * kv);
    }
  }
  __syncthreads();   // KtT built; Kh/Kl_ now dead -> DT/WT overlay safe

  const float gL = __expf(Ef[63]);   // Ef row 0 intact (KtT occupies rows 32..63 only)
  {
    bf16* myT = wid ? WT : DT;
    #pragma unroll
    for (int s4 = 0; s4 < 16; ++s4){
      bf16x4 v4;
      v4[0]=(bf16)d[s4*4+0]; v4[1]=(bf16)d[s4*4+1];
      v4[2]=(bf16)d[s4*4+2]; v4[3]=(bf16)d[s4*4+3];
      *(bf16x4*)&myT[lane*64 + ((s4*4) ^ ((lane&7)<<3))] = v4;
    }
    bf16* myG = wid ? Wg : Dg;
    #pragma unroll
    for (int t = 0; t < 64; ++t)
      myG[cbase + (size_t)t*64 + lane] = (bf16)d[t];
  }
  __syncthreads();

  // P^T[j][i] = gamma_L*I - sum_t K_til[t][j]*Wsol[t][i]  (wave0, MFMA, packed hi|lo dword out)
  // B[i][j]   =              sum_t Dsol[t][i]*K_til[t][j]  (wave1, MFMA, bf16 out)
  if (wid == 0){
    #pragma unroll
    for (int tj = 0; tj < 4; ++tj)
      #pragma unroll
      for (int ti = 0; ti < 4; ++ti){
        f32x4 acc = f32x4_zero();
        #pragma unroll
        for (int kk = 0; kk < 2; ++kk)
          acc = mfma16x16x32(fragSwz(KtT, 16*tj, kk, lane), fragSwz(WT, 16*ti, kk, lane), acc);
        #pragma unroll
        for (int r = 0; r < 4; ++r){
          int row = 16*tj + (lane>>4)*4 + r, col = 16*ti + (lane&15);
          float v = ((row == col) ? gL : 0.f) - acc[r];
          Pg[cbase + (size_t)row*64 + col] = pack2(v);
        }
      }
  } else {
    #pragma unroll
    for (int ti = 0; ti < 4; ++ti)
      #pragma unroll
      for (int tj = 0; tj < 4; ++tj){
        f32x4 acc = f32x4_zero();
        #pragma unroll
        for (int kk = 0; kk < 2; ++kk)
          acc = mfma16x16x32(fragSwz(DT, 16*ti, kk, lane), fragSwz(KtT, 16*tj, kk, lane), acc);
        #pragma unroll
        for (int r = 0; r < 4; ++r){
          int row = 16*ti + (lane>>4)*4 + r, col = 16*tj + (lane&15);
          Bg[cbase + (size_t)row*64 + col] = (bf16)acc[r];
        }
      }
  }
}

// ---------------------------------------------------------------- K4a: segment composition (256 blocks: 8 seg x 32 chains)
__global__ __launch_bounds__(256) void k_phaseB1(const uint32_t* __restrict__ Pg,
                                                 const bf16* __restrict__ Bg,
                                                 float* __restrict__ PsegT, float* __restrict__ BsegF){
  __shared__ bf16 PaccH[4096], PaccL[4096], BaccH[4096], BaccL[4096];
  __shared__ bf16 PcH[4096], PcL[4096];
  __shared__ bf16 BcS[4096];
  const int tid = threadIdx.x, lane = tid & 63, w = tid >> 6;
  const int seg = blockIdx.x;
  const size_t chain = blockIdx.y;
  f32x4 Pr[4], Br[4];
  #pragma unroll
  for (int it = 0; it < 4; ++it){
    #pragma unroll
    for (int r = 0; r < 4; ++r){
      int row = 16*w + (lane>>4)*4 + r, col = 16*it + (lane&15);
      Pr[it][r] = (row == col) ? 1.f : 0.f;   // Pacc = I
      Br[it][r] = 0.f;                        // Bacc = 0
    }
  }
  for (int i = 0; i < 8; ++i){
    const size_t cb = (chain*64 + (size_t)seg*8 + i)*4096;
    #pragma unroll
    for (int it = 0; it < 4; ++it)
      #pragma unroll
      for (int r = 0; r < 4; ++r){
        int row = 16*w + (lane>>4)*4 + r, col = 16*it + (lane&15);
        bf2 sp = split2(Pr[it][r]); PaccH[row*64+col] = sp.h; PaccL[row*64+col] = sp.l;
        bf2 sb = split2(Br[it][r]); BaccH[row*64+col] = sb.h; BaccL[row*64+col] = sb.l;
      }
    __syncthreads();   // prev iter's MFMA done -> safe to overwrite PcH/L
    for (int j = tid; j < 1024; j += 256){
      uint4 p = ((const uint4*)(Pg + cb))[j];   // 4 packed elems
      uint2 hh, ll;
      hh.x = (p.x & 0xFFFFu) | (p.y << 16);
      ll.x = (p.x >> 16)     | (p.y & 0xFFFF0000u);
      hh.y = (p.z & 0xFFFFu) | (p.w << 16);
      ll.y = (p.z >> 16)     | (p.w & 0xFFFF0000u);
      ((uint2*)PcH)[j] = hh;
      ((uint2*)PcL)[j] = ll;
    }
    for (int j = tid; j < 512; j += 256)
      ((uint4*)BcS)[j] = ((const uint4*)(Bg + cb))[j];
    __syncthreads();
    f32x4 nP[4], nB[4];
    #pragma unroll
    for (int it = 0; it < 4; ++it){ nP[it] = f32x4_zero(); nB[it] = f32x4_zero(); }
    #pragma unroll
    for (int kk = 0; kk < 2; ++kk){
      bf16x8 aPH = frag64(PaccH, 16*w, kk, lane), aPL = frag64(PaccL, 16*w, kk, lane);
      bf16x8 aBH = frag64(BaccH, 16*w, kk, lane), aBL = frag64(BaccL, 16*w, kk, lane);
      #pragma unroll
      for (int it = 0; it < 4; ++it){
        bf16x8 bH = frag64(PcH, 16*it, kk, lane), bL = frag64(PcL, 16*it, kk, lane);
        nP[it] = mfma16x16x32(aPH, bH, nP[it]);
        nP[it] = mfma16x16x32(aPH, bL, nP[it]);
        nP[it] = mfma16x16x32(aPL, bH, nP[it]);
        nB[it] = mfma16x16x32(aBH, bH, nB[it]);
        nB[it] = mfma16x16x32(aBH, bL, nB[it]);
        nB[it] = mfma16x16x32(aBL, bH, nB[it]);
      }
    }
    #pragma unroll
    for (int it = 0; it < 4; ++it)
      #pragma unroll
      for (int r = 0; r < 4; ++r){
        int row = 16*w + (lane>>4)*4 + r, col = 16*it + (lane&15);
        Pr[it][r] = nP[it][r];
        Br[it][r] = nB[it][r] + (float)BcS[row*64 + col];
      }
  }
  const size_t sb = (chain*8 + seg)*4096;
  #pragma unroll
  for (int it = 0; it < 4; ++it)
    #pragma unroll
    for (int r = 0; r < 4; ++r){
      int row = 16*w + (lane>>4)*4 + r, col = 16*it + (lane&15);
      PsegT[sb + (size_t)col*64 + row] = Pr[it][r];   // transposed (B-operand layout)
      BsegF[sb + (size_t)row*64 + col] = Br[it][r];   // natural
    }
}

// ---------------------------------------------------------------- K4b: segment-level scan (32 blocks, 8 steps)
__global__ __launch_bounds__(256) void k_phaseB2(const float* __restrict__ PsegT, const float* __restrict__ BsegF,
                                                 float* __restrict__ S0g){
  __shared__ bf16 Sh[4096], Sl[4096], Ph[4096], Pl[4096];
  __shared__ float Bf[4096];
  const int tid = threadIdx.x, lane = tid & 63, w = tid >> 6;
  const size_t bid = blockIdx.x;
  f32x4 Sr[4];
  #pragma unroll
  for (int it = 0; it < 4; ++it) Sr[it] = f32x4_zero();
  for (int seg = 0; seg < 8; ++seg){
    const size_t sb  = (bid*8 + seg)*4096;
    const size_t s0b = (bid*64 + (size_t)seg*8)*4096;
    #pragma unroll
    for (int it = 0; it < 4; ++it)
      #pragma unroll
      for (int r = 0; r < 4; ++r){
        int row = 16*w + (lane>>4)*4 + r, col = 16*it + (lane&15);
        S0g[s0b + (size_t)row*64 + col] = Sr[it][r];
        bf2 sp = split2(Sr[it][r]); Sh[row*64+col] = sp.h; Sl[row*64+col] = sp.l;
      }
    __syncthreads();
    for (int j = tid; j < 1024; j += 256){
      float4 pv = ((const float4*)(PsegT + sb))[j];
      bf16x4 ph, pl;
      bf2 u0 = split2(pv.x); ph[0]=u0.h; pl[0]=u0.l;
      bf2 u1 = split2(pv.y); ph[1]=u1.h; pl[1]=u1.l;
      bf2 u2 = split2(pv.z); ph[2]=u2.h; pl[2]=u2.l;
      bf2 u3 = split2(pv.w); ph[3]=u3.h; pl[3]=u3.l;
      ((bf16x4*)Ph)[j] = ph; ((bf16x4*)Pl)[j] = pl;
      ((float4*)Bf)[j] = ((const float4*)(BsegF + sb))[j];
    }
    __syncthreads();
    f32x4 nS[4];
    #pragma unroll
    for (int it = 0; it < 4; ++it) nS[it] = f32x4_zero();
    #pragma unroll
    for (int kk = 0; kk < 2; ++kk){
      bf16x8 aH = frag64(Sh, 16*w, kk, lane), aL = frag64(Sl, 16*w, kk, lane);
      #pragma unroll
      for (int it = 0; it < 4; ++it){
        bf16x8 bH = frag64(Ph, 16*it, kk, lane), bL = frag64(Pl, 16*it, kk, lane);
        nS[it] = mfma16x16x32(aH, bH, nS[it]);
        nS[it] = mfma16x16x32(aH, bL, nS[it]);
        nS[it] = mfma16x16x32(aL, bH, nS[it]);
      }
    }
    #pragma unroll
    for (int it = 0; it < 4; ++it)
      #pragma unroll
      for (int r = 0; r < 4; ++r){
        int row = 16*w + (lane>>4)*4 + r, col = 16*it + (lane&15);
        Sr[it][r] = nS[it][r] + Bf[row*64 + col];
      }
  }
}

// ---------------------------------------------------------------- K4c: within-segment replay (256 blocks, 7 steps)
__global__ __launch_bounds__(256) void k_phaseB3(const uint32_t* __restrict__ Pg,
                                                 const bf16* __restrict__ Bg,
                                                 float* __restrict__ S0g){
  __shared__ bf16 Sh[4096], Sl[4096], Ph[4096], Pl[4096];
  __shared__ bf16 BcS[4096];
  const int tid = threadIdx.x, lane = tid & 63, w = tid >> 6;
  const int seg = blockIdx.x;
  const size_t chain = blockIdx.y;
  const size_t segbase = chain*64 + (size_t)seg*8;
  f32x4 Sr[4];
  #pragma unroll
  for (int it = 0; it < 4; ++it)
    #pragma unroll
    for (int r = 0; r < 4; ++r){
      int row = 16*w + (lane>>4)*4 + r, col = 16*it + (lane&15);
      Sr[it][r] = S0g[segbase*4096 + (size_t)row*64 + col];
    }
  for (int i = 0; i < 7; ++i){
    const size_t cb = (segbase + i)*4096;
    #pragma unroll
    for (int it = 0; it < 4; ++it)
      #pragma unroll
      for (int r = 0; r < 4; ++r){
        int row = 16*w + (lane>>4)*4 + r, col = 16*it + (lane&15);
        bf2 sp = split2(Sr[it][r]); Sh[row*64+col] = sp.h; Sl[row*64+col] = sp.l;
      }
    __syncthreads();
    for (int j = tid; j < 1024; j += 256){
      uint4 p = ((const uint4*)(Pg + cb))[j];
      uint2 hh, ll;
      hh.x = (p.x & 0xFFFFu) | (p.y << 16);
      ll.x = (p.x >> 16)     | (p.y & 0xFFFF0000u);
      hh.y = (p.z & 0xFFFFu) | (p.w << 16);
      ll.y = (p.z >> 16)     | (p.w & 0xFFFF0000u);
      ((uint2*)Ph)[j] = hh;
      ((uint2*)Pl)[j] = ll;
    }
    for (int j = tid; j < 512; j += 256)
      ((uint4*)BcS)[j] = ((const uint4*)(Bg + cb))[j];
    __syncthreads();
    f32x4 nS[4];
    #pragma unroll
    for (int it = 0; it < 4; ++it) nS[it] = f32x4_zero();
    #pragma unroll
    for (int kk = 0; kk < 2; ++kk){
      bf16x8 aH = frag64(Sh, 16*w, kk, lane), aL = frag64(Sl, 16*w, kk, lane);
      #pragma unroll
      for (int it = 0; it < 4; ++it){
        bf16x8 bH = frag64(Ph, 16*it, kk, lane), bL = frag64(Pl, 16*it, kk, lane);
        nS[it] = mfma16x16x32(aH, bH, nS[it]);
        nS[it] = mfma16x16x32(aH, bL, nS[it]);
        nS[it] = mfma16x16x32(aL, bH, nS[it]);
      }
    }
    const size_t outb = (segbase + i + 1)*4096;
    #pragma unroll
    for (int it = 0; it < 4; ++it)
      #pragma unroll
      for (int r = 0; r < 4; ++r){
        int row = 16*w + (lane>>4)*4 + r, col = 16*it + (lane&15);
        float v = nS[it][r] + (float)BcS[row*64 + col];
        Sr[it][r] = v;
        S0g[outb + (size_t)row*64 + col] = v;
      }
  }
}

// ---------------------------------------------------------------- K5: phase C, outputs + fused RMSNorm/gate (2048 blocks)
__global__ __launch_bounds__(256, 2) void k_phaseC(
    const bf16* __restrict__ qhp, const bf16* __restrict__ qlp,
    const bf16* __restrict__ khp, const bf16* __restrict__ klp,
    const bf16* __restrict__ gf, const float* __restrict__ logA,
    const float* __restrict__ S0g, const bf16* __restrict__ Wg, const bf16* __restrict__ Dg,
    const float* __restrict__ rms_w, bf16* __restrict__ yh, bf16* __restrict__ yl){
  __shared__ bf16 Qh[4096], Ql[4096], Kh[4096], Klo[4096];
  __shared__ bf16 Wl_[4096], Dl_[4096];
  __shared__ bf16 S0h[4096], S0l[4096];
  __shared__ bf16 AAg[4096];
  __shared__ bf16 BDt[4096];
  const int tid = threadIdx.x, lane = tid & 63, w = tid >> 6;
  const int c = blockIdx.x, h = blockIdx.y, b = blockIdx.z;
  const size_t tokbase = (size_t)b*4096 + (size_t)c*64;
  const size_t cbase = ((size_t)((b*16 + h)*64 + c)) * 4096;

  { // async stage Q/K (hi/lo) + Wg/Dg with pre-swizzled source
    const int chunk = tid & 7, r0 = tid >> 3;   // r0 0..31; wave w rows 8w..8w+7 per round
    #pragma unroll
    for (int rr = 0; rr < 2; ++rr){
      const int row = 32*rr + r0;
      const int dbase = (32*rr + 8*w)*64;
      const size_t g = (tokbase + row)*1024 + (size_t)h*64 + 8*(chunk ^ (row & 7));
      GLD_LDS16(&qhp[g], &Qh[dbase]);
      if (qlp) GLD_LDS16(&qlp[g], &Ql[dbase]);
      GLD_LDS16(&khp[g], &Kh[dbase]);
      if (klp) GLD_LDS16(&klp[g], &Klo[dbase]);
      const size_t gg = cbase + (size_t)row*64 + 8*(chunk ^ (row & 7));
      GLD_LDS16(&Wg[gg], &Wl_[dbase]);
      GLD_LDS16(&Dg[gg], &Dl_[dbase]);
    }
    if (!qlp){
      uint4 z4; z4.x=0; z4.y=0; z4.z=0; z4.w=0;
      for (int z = tid; z < 512; z += 256){ ((uint4*)Ql)[z] = z4; ((uint4*)Klo)[z] = z4; }
    }
  }
  for (int i = tid; i < 1024; i += 256){
    float4 v = ((const float4*)(S0g + cbase))[i];
    bf16x4 sh, sl;
    bf2 t0 = split2(v.x); sh[0]=t0.h; sl[0]=t0.l;
    bf2 t1 = split2(v.y); sh[1]=t1.h; sl[1]=t1.l;
    bf2 t2 = split2(v.z); sh[2]=t2.h; sl[2]=t2.l;
    bf2 t3 = split2(v.w); sh[3]=t3.h; sl[3]=t3.l;
    int t = i >> 4, off = ((i&15)*4) ^ ((t&7)<<3);
    *(bf16x4*)&S0h[t*64 + off] = sh;
    *(bf16x4*)&S0l[t*64 + off] = sl;
  }
  // per-wave redundant lg cumsum
  float la = logA[(tokbase + lane)*16 + h];
  #pragma unroll
  for (int dlt = 1; dlt < 64; dlt <<= 1){
    float o = __shfl_up(la, dlt);
    if (lane >= dlt) la += o;
  }
  __syncthreads();

  { // AAg = mask_incl(Gamma .* QK^T), 3-product
    const int t0 = 16*w;
    #pragma unroll
    for (int tu = 0; tu < 4; ++tu){
      f32x4 accm = f32x4_zero();
      #pragma unroll
      for (int kk = 0; kk < 2; ++kk){
        bf16x8 aH = fragSwz(Qh,  t0,    kk, lane);
        bf16x8 aL = fragSwz(Ql,  t0,    kk, lane);
        bf16x8 bH = fragSwz(Kh,  16*tu, kk, lane);
        bf16x8 bL = fragSwz(Klo, 16*tu, kk, lane);
        accm = mfma16x16x32(aH, bH, accm);
        accm = mfma16x16x32(aH, bL, accm);
        accm = mfma16x16x32(aL, bH, accm);
      }
      #pragma unroll
      for (int r = 0; r < 4; ++r){
        int row = t0 + (lane>>4)*4 + r, col = 16*tu + (lane&15);
        float lgr = __shfl(la, row), lgc = __shfl(la, col);
        float v = (col <= row) ? accm[r]*__expf(lgr - lgc) : 0.f;
        AAg[row*64 + (col ^ ((row&7)<<3))] = (bf16)v;
      }
    }
  }
  { // BDt[i][tau] = Dloc[tau][i] - (S0 W_hat^T)[i][tau]
    const int i0 = 16*w;
    #pragma unroll
    for (int tu = 0; tu < 4; ++tu){
      f32x4 accm = f32x4_zero();
      #pragma unroll
      for (int kk = 0; kk < 2; ++kk){
        bf16x8 aH = fragSwz(S0h, i0,    kk, lane);
        bf16x8 aL = fragSwz(S0l, i0,    kk, lane);
        bf16x8 bb = fragSwz(Wl_, 16*tu, kk, lane);
        accm = mfma16x16x32(aH, bb, accm);
        accm = mfma16x16x32(aL, bb, accm);
      }
      #pragma unroll
      for (int r = 0; r < 4; ++r){
        int row = i0 + (lane>>4)*4 + r, col = 16*tu + (lane&15);
        float v = (float)Dl_[col*64 + (row ^ ((col&7)<<3))] - accm[r];
        BDt[row*64 + (col ^ ((row&7)<<3))] = (bf16)v;
      }
    }
  }
  __syncthreads();
  for (int i = tid; i < 4096; i += 256){
    int t = i >> 6;                              // uniform per wave per iteration
    float gq = __expf(__shfl(la, t));
    float v = gq * ((float)Qh[i] + (float)Ql[i]);  // swizzle is within-row: row scale layout-agnostic
    bf2 sp = split2(v);
    Qh[i] = sp.h; Ql[i] = sp.l;
  }
  __syncthreads();
  {
    const int t0 = 16*w;
    f32x4 o_acc[4];
    #pragma unroll
    for (int it = 0; it < 4; ++it) o_acc[it] = f32x4_zero();
    #pragma unroll
    for (int kk = 0; kk < 2; ++kk){
      bf16x8 aQh = fragSwz(Qh, t0, kk, lane);
      bf16x8 aQl = fragSwz(Ql, t0, kk, lane);
      bf16x8 aA  = fragSwz(AAg, t0, kk, lane);
      #pragma unroll
      for (int it = 0; it < 4; ++it){
        bf16x8 bSh = fragSwz(S0h, 16*it, kk, lane);
        bf16x8 bSl = fragSwz(S0l, 16*it, kk, lane);
        bf16x8 bD  = fragSwz(BDt, 16*it, kk, lane);
        f32x4 t = o_acc[it];
        t = mfma16x16x32(aQh, bSh, t);
        t = mfma16x16x32(aQh, bSl, t);
        t = mfma16x16x32(aQl, bSh, t);
        t = mfma16x16x32(aA,  bD,  t);
        o_acc[it] = t;
      }
    }
    float rw[4];
    #pragma unroll
    for (int it = 0; it < 4; ++it) rw[it] = rms_w[16*it + (lane&15)];
    #pragma unroll
    for (int r = 0; r < 4; ++r){
      float ss = 0.f;
      #pragma unroll
      for (int it = 0; it < 4; ++it) ss += o_acc[it][r]*o_acc[it][r];
      ss += __shfl_xor(ss, 1); ss += __shfl_xor(ss, 2);
      ss += __shfl_xor(ss, 4); ss += __shfl_xor(ss, 8);
      const float scale = rsqrtf(ss*(1.f/64.f) + 1e-6f);
      const int row = t0 + (lane>>4)*4 + r;
      const size_t tok = tokbase + row;
      #pragma unroll
      for (int it = 0; it < 4; ++it){
        const int col = 16*it + (lane&15);
        float g = (float)gf[tok*1024 + h*64 + col];
        float sg = g / (1.f + __expf(-g));
        float v = o_acc[it][r]*scale*rw[it]*sg;
        bf2 sp = split2(v);
        yh[tok*1024 + h*64 + col] = sp.h;
        yl[tok*1024 + h*64 + col] = sp.l;
      }
    }
  }
}

// ---------------------------------------------------------------- launcher
extern "C" void kernel_launch(void* const* d_in, const int* in_sizes, int n_in,
                              void* d_out, int out_size, void* d_ws, size_t ws_size,
                              hipStream_t stream){
  const float* x     = (const float*)d_in[0];
  const float* Wq    = (const float*)d_in[1];
  const float* Wk    = (const float*)d_in[2];
  const float* Wv    = (const float*)d_in[3];
  const float* Wa    = (const float*)d_in[4];
  const float* Wb    = (const float*)d_in[5];
  const float* A_log = (const float*)d_in[6];
  const float* dt_b  = (const float*)d_in[7];
  const float* Wgt   = (const float*)d_in[8];
  const float* Wo    = (const float*)d_in[9];
  const float* rms_w = (const float*)d_in[10];

  const bool BIG = ws_size >= (size_t)215000000;

  char* ws = (char*)d_ws;
  size_t off = 0;
  auto alloc = [&](size_t bytes)->char*{
    char* p = ws + off;
    off += (bytes + 255) & ~(size_t)255;
    return p;
  };
  const size_t PLANE = (size_t)8192*1024*2;   // bf16 activation plane (16 MiB)
  const size_t WPL   = (size_t)1024*1024*2;   // bf16 weight plane (2 MiB)
  bf16* xh  = (bf16*)alloc(PLANE);            // region also hosts packed Pg (A->B3), then yh
  bf16* xl  = (bf16*)alloc(PLANE);            // (xh+xl contiguous: PLANE is 256-aligned)
  bf16* wqh = (bf16*)alloc(WPL); bf16* wql = (bf16*)alloc(WPL);   // wqh..wgl also hosts Bg
  bf16* wkh = (bf16*)alloc(WPL); bf16* wkl = (bf16*)alloc(WPL);
  bf16* wvh = (bf16*)alloc(WPL); bf16* wvl = (bf16*)alloc(WPL);
  bf16* wgh = (bf16*)alloc(WPL); bf16* wgl = (bf16*)alloc(WPL);
  bf16* woh = (bf16*)alloc(WPL); bf16* wol = (bf16*)alloc(WPL);
  bf16* WabTh = (bf16*)alloc((size_t)32*1024*2);
  bf16* WabTl = (bf16*)alloc((size_t)32*1024*2);
  // q/k as hi/lo bf16 split planes (hi-only in SMALL)
  bf16* qh = nullptr; bf16* ql = nullptr;
  bf16* kh = nullptr; bf16* kl = nullptr;
  if (BIG){
    qh = (bf16*)alloc(PLANE); ql = (bf16*)alloc(PLANE);
    kh = (bf16*)alloc(PLANE); kl = (bf16*)alloc(PLANE);
  } else {
    qh = (bf16*)alloc(PLANE);
    kh = (bf16*)alloc(PLANE);
  }
  float* vf  = (float*)alloc((size_t)8192*1024*4);  // dead after phase A -> hosts S0g
  bf16* gfb  = (bf16*)alloc(PLANE);
  float* logA  = (float*)alloc((size_t)8192*16*4);
  float* betap = (float*)alloc((size_t)8192*16*4);
  bf16* Wg  = (bf16*)alloc((size_t)2048*4096*2);
  bf16* Dg  = (bf16*)alloc((size_t)2048*4096*2);
  uint32_t* Pg = (uint32_t*)xh;       // packed hi|lo P plane, 33.5 MB spanning xh+xl
  float* S0g = vf;                    // 33.5 MiB fp32 (vf dead after phase A)
  bf16* Bg   = wqh;                   // 16 MiB bf16 (projection weights dead)
  float* PsegT = (float*)d_out;       // 4 MiB scratch in d_out (overwritten by final GEMM)
  float* BsegF = (float*)d_out + 1048576;  // next 4 MiB
  bf16* yh = xh;                      // phase C outputs (Pg dead after B3)
  bf16* yl = xl;

  k_cvt_x<<<8192, 256, 0, stream>>>(x, xh, xl, 2097152);
  k_transpose_w5<<<dim3(32,32,5), 256, 0, stream>>>(Wq, Wk, Wv, Wgt, Wo, wqh);
  k_transpose_ab<<<128, 256, 0, stream>>>(Wa, Wb, WabTh, WabTl);

  k_gemm_qkvg<<<dim3(64,32), 256, 0, stream>>>(xh, wqh, qh, ql, kh, kl, vf, gfb);

  k_ab_gemm<<<256, 256, 0, stream>>>(xh, xl, WabTh, WabTl, A_log, dt_b, logA, betap);

  k_phaseA<<<dim3(64,16,2), 128, 0, stream>>>(kh, kl, vf, logA, betap, Wg, Dg, Pg, Bg);
  k_phaseB1<<<dim3(8,32), 256, 0, stream>>>(Pg, Bg, PsegT, BsegF);
  k_phaseB2<<<32, 256, 0, stream>>>(PsegT, BsegF, S0g);
  k_phaseB3<<<dim3(8,32), 256, 0, stream>>>(Pg, Bg, S0g);
  k_phaseC<<<dim3(64,16,2), 256, 0, stream>>>(qh, ql, kh, kl, gfb, logA, S0g, Wg, Dg, rms_w, yh, yl);

  k_gemm3<<<dim3(64,8), 256, 0, stream>>>(yh, yl, woh, wol, nullptr, (float*)d_out);
}